// Round 1
// baseline (1060.222 us; speedup 1.0000x reference)
//
#include <hip/hip_runtime.h>
#include <math.h>

#define FIN 128   // input features (layer1 K, layer2 K)
#define F1  128   // H1*C1 = layer1 output width
#define C2  64    // layer2 output width
#define NEG 0.2f  // leaky_relu negative slope

// ---------------- CSR build (by dst, self-loops appended) ----------------
__global__ void count_deg_kernel(const int* __restrict__ ei, int* __restrict__ cnt,
                                 int E, int N) {
  int e = blockIdx.x * blockDim.x + threadIdx.x;
  if (e >= E + N) return;
  int dst = (e < E) ? ei[E + e] : (e - E);
  atomicAdd(&cnt[dst], 1);
}

// single-block exclusive scan: indptr[v] = sum_{u<v} cnt[u]; cursor gets same.
// cnt and cursor may alias (read-before-write per element, same thread).
__global__ __launch_bounds__(1024) void scan_kernel(const int* __restrict__ cnt,
                                                    int* __restrict__ indptr,
                                                    int* __restrict__ cursor, int N) {
  __shared__ int sums[1024];
  int t = threadIdx.x;
  int chunk = (N + 1023) >> 10;
  int b = t * chunk;
  int e = min(N, b + chunk);
  int s = 0;
  for (int i = b; i < e; ++i) s += cnt[i];
  sums[t] = s;
  __syncthreads();
  for (int off = 1; off < 1024; off <<= 1) {
    int val = (t >= off) ? sums[t - off] : 0;
    __syncthreads();
    sums[t] += val;
    __syncthreads();
  }
  int prefix = (t == 0) ? 0 : sums[t - 1];
  for (int i = b; i < e; ++i) {
    int c = cnt[i];          // read before overwrite (cursor may alias cnt)
    indptr[i] = prefix;
    cursor[i] = prefix;
    prefix += c;
  }
  if (t == 1023) indptr[N] = prefix;
}

__global__ void fill_csr_kernel(const int* __restrict__ ei, int* __restrict__ cursor,
                                int* __restrict__ csr, int E, int N) {
  int e = blockIdx.x * blockDim.x + threadIdx.x;
  if (e >= E + N) return;
  int src, dst;
  if (e < E) { src = ei[e]; dst = ei[E + e]; }
  else       { src = e - E; dst = src; }
  int pos = atomicAdd(&cursor[dst], 1);
  csr[pos] = src;
}

// ---------------- fp32 GEMM: out[M,Ncols] = A[M,128] @ W[128,Ncols] + bias ----------------
// 64x64 tile, 256 threads, 4x4 per thread, K staged in 16-chunks.
__global__ __launch_bounds__(256) void gemm_bias_kernel(
    const float* __restrict__ A, const float* __restrict__ W,
    const float* __restrict__ bias, float* __restrict__ out,
    int M, int Ncols) {
  __shared__ float As[16][68];  // [k][m], +4 pad keeps 16B alignment, kills conflicts
  __shared__ float Ws[16][68];  // [k][c]
  const int tid = threadIdx.x;
  const int r0 = blockIdx.x * 64;
  const int c0 = blockIdx.y * 64;
  const int tm = tid >> 4;          // 0..15 row group
  const int tc = tid & 15;          // 0..15 col group
  const int la_row = tid >> 2;      // 0..63
  const int la_k4  = (tid & 3) << 2;
  const int lw_k   = tid >> 4;      // 0..15
  const int lw_c4  = (tid & 15) << 2;
  const int arow = min(r0 + la_row, M - 1);  // clamp; stores are guarded
  float acc[4][4] = {{0.f, 0.f, 0.f, 0.f}, {0.f, 0.f, 0.f, 0.f},
                     {0.f, 0.f, 0.f, 0.f}, {0.f, 0.f, 0.f, 0.f}};
  for (int k0 = 0; k0 < FIN; k0 += 16) {
    const float4 av = *(const float4*)(A + (size_t)arow * FIN + k0 + la_k4);
    const float4 wv = *(const float4*)(W + (size_t)(k0 + lw_k) * Ncols + c0 + lw_c4);
    __syncthreads();
    As[la_k4 + 0][la_row] = av.x;
    As[la_k4 + 1][la_row] = av.y;
    As[la_k4 + 2][la_row] = av.z;
    As[la_k4 + 3][la_row] = av.w;
    *(float4*)(&Ws[lw_k][lw_c4]) = wv;
    __syncthreads();
#pragma unroll
    for (int kk = 0; kk < 16; ++kk) {
      const float4 a4 = *(const float4*)(&As[kk][tm << 2]);
      const float4 w4 = *(const float4*)(&Ws[kk][tc << 2]);
      acc[0][0] = fmaf(a4.x, w4.x, acc[0][0]);
      acc[0][1] = fmaf(a4.x, w4.y, acc[0][1]);
      acc[0][2] = fmaf(a4.x, w4.z, acc[0][2]);
      acc[0][3] = fmaf(a4.x, w4.w, acc[0][3]);
      acc[1][0] = fmaf(a4.y, w4.x, acc[1][0]);
      acc[1][1] = fmaf(a4.y, w4.y, acc[1][1]);
      acc[1][2] = fmaf(a4.y, w4.z, acc[1][2]);
      acc[1][3] = fmaf(a4.y, w4.w, acc[1][3]);
      acc[2][0] = fmaf(a4.z, w4.x, acc[2][0]);
      acc[2][1] = fmaf(a4.z, w4.y, acc[2][1]);
      acc[2][2] = fmaf(a4.z, w4.z, acc[2][2]);
      acc[2][3] = fmaf(a4.z, w4.w, acc[2][3]);
      acc[3][0] = fmaf(a4.w, w4.x, acc[3][0]);
      acc[3][1] = fmaf(a4.w, w4.y, acc[3][1]);
      acc[3][2] = fmaf(a4.w, w4.z, acc[3][2]);
      acc[3][3] = fmaf(a4.w, w4.w, acc[3][3]);
    }
  }
  const float4 b4 = *(const float4*)(bias + c0 + (tc << 2));
#pragma unroll
  for (int i = 0; i < 4; ++i) {
    int r = r0 + (tm << 2) + i;
    if (r < M) {
      float4 o;
      o.x = acc[i][0] + b4.x;
      o.y = acc[i][1] + b4.y;
      o.z = acc[i][2] + b4.z;
      o.w = acc[i][3] + b4.w;
      *(float4*)(out + (size_t)r * Ncols + c0 + (tc << 2)) = o;
    }
  }
}

// ---------------- layer 1 fused attention: one block per dst node ----------------
// 128 threads: t -> (head=t>>4, chan=t&15). Online softmax over incoming edges.
// Epilogue: +bias, ELU, write h.
__global__ __launch_bounds__(128) void attn1_kernel(
    const float* __restrict__ xl, const float* __restrict__ xr,
    const float* __restrict__ att, const float* __restrict__ bias,
    const int* __restrict__ indptr, const int* __restrict__ csr,
    float* __restrict__ hout) {
  const int v = blockIdx.x;
  const int t = threadIdx.x;
  const float xrv  = xr[(size_t)v * F1 + t];
  const float attv = att[t];
  const int beg = indptr[v];
  const int end = indptr[v + 1];
  float m = -INFINITY, l = 0.f, acc = 0.f;
  for (int e = beg; e < end; ++e) {
    const int s = csr[e];
    const float xv = xl[(size_t)s * F1 + t];
    const float tsum = xv + xrv;
    float term = (tsum > 0.f ? tsum : NEG * tsum) * attv;
    term += __shfl_xor(term, 1);
    term += __shfl_xor(term, 2);
    term += __shfl_xor(term, 4);
    term += __shfl_xor(term, 8);
    const float score = term;                 // uniform over the 16-lane head group
    const float newm = fmaxf(m, score);
    const float sc = __expf(m - newm);        // m=-inf first iter -> 0
    const float p  = __expf(score - newm);
    l   = l * sc + p;
    acc = acc * sc + p * xv;
    m = newm;
  }
  float res = acc / l + bias[t];
  res = res > 0.f ? res : expm1f(res);        // ELU
  hout[(size_t)v * F1 + t] = res;
}

// ---------------- layer 2 fused attention: 1 head x 64 chans, one wave per node ----------------
__global__ __launch_bounds__(64) void attn2_kernel(
    const float* __restrict__ xl, const float* __restrict__ xr,
    const float* __restrict__ att, const float* __restrict__ bias,
    const int* __restrict__ indptr, const int* __restrict__ csr,
    float* __restrict__ out) {
  const int v = blockIdx.x;
  const int t = threadIdx.x;
  const float xrv  = xr[(size_t)v * C2 + t];
  const float attv = att[t];
  const int beg = indptr[v];
  const int end = indptr[v + 1];
  float m = -INFINITY, l = 0.f, acc = 0.f;
  for (int e = beg; e < end; ++e) {
    const int s = csr[e];
    const float xv = xl[(size_t)s * C2 + t];
    const float tsum = xv + xrv;
    float term = (tsum > 0.f ? tsum : NEG * tsum) * attv;
    term += __shfl_xor(term, 1);
    term += __shfl_xor(term, 2);
    term += __shfl_xor(term, 4);
    term += __shfl_xor(term, 8);
    term += __shfl_xor(term, 16);
    term += __shfl_xor(term, 32);
    const float score = term;
    const float newm = fmaxf(m, score);
    const float sc = __expf(m - newm);
    const float p  = __expf(score - newm);
    l   = l * sc + p;
    acc = acc * sc + p * xv;
    m = newm;
  }
  out[(size_t)v * C2 + t] = acc / l + bias[t];
}

extern "C" void kernel_launch(void* const* d_in, const int* in_sizes, int n_in,
                              void* d_out, int out_size, void* d_ws, size_t ws_size,
                              hipStream_t stream) {
  const float* x     = (const float*)d_in[0];
  const int*   ei    = (const int*)d_in[1];   // [2,E] int32
  const float* Wl1   = (const float*)d_in[2];
  const float* bl1   = (const float*)d_in[3];
  const float* Wr1   = (const float*)d_in[4];
  const float* br1   = (const float*)d_in[5];
  const float* att1  = (const float*)d_in[6];
  const float* bias1 = (const float*)d_in[7];
  const float* Wl2   = (const float*)d_in[8];
  const float* bl2   = (const float*)d_in[9];
  const float* Wr2   = (const float*)d_in[10];
  const float* br2   = (const float*)d_in[11];
  const float* att2  = (const float*)d_in[12];
  const float* bias2 = (const float*)d_in[13];

  const int N  = in_sizes[0] / FIN;   // 100000
  const int E  = in_sizes[1] / 2;     // 1600000
  const int ET = E + N;               // with self loops

  // workspace layout (fp32 elements)
  float* xl1  = (float*)d_ws;                  // N*128
  float* xr1  = xl1 + (size_t)N * F1;          // N*128
  float* hbuf = xr1 + (size_t)N * F1;          // N*128
  int* indptr = (int*)(hbuf + (size_t)N * F1); // N+1
  int* cursor = indptr + (N + 1);              // N (doubles as cnt)
  int* csr    = cursor + N;                    // ET
  float* xl2  = xl1;                           // reuse layer1 region: N*64
  float* xr2  = xl1 + (size_t)N * C2;          // N*64
  float* out  = (float*)d_out;

  const int tb = 256;
  const int eblocks = (ET + tb - 1) / tb;

  hipMemsetAsync(cursor, 0, (size_t)N * sizeof(int), stream);
  count_deg_kernel<<<eblocks, tb, 0, stream>>>(ei, cursor, E, N);
  scan_kernel<<<1, 1024, 0, stream>>>(cursor, indptr, cursor, N);
  fill_csr_kernel<<<eblocks, tb, 0, stream>>>(ei, cursor, csr, E, N);

  dim3 g1((N + 63) / 64, F1 / 64);
  gemm_bias_kernel<<<g1, 256, 0, stream>>>(x, Wl1, bl1, xl1, N, F1);
  gemm_bias_kernel<<<g1, 256, 0, stream>>>(x, Wr1, br1, xr1, N, F1);

  attn1_kernel<<<N, 128, 0, stream>>>(xl1, xr1, att1, bias1, indptr, csr, hbuf);

  dim3 g2((N + 63) / 64, C2 / 64);
  gemm_bias_kernel<<<g2, 256, 0, stream>>>(hbuf, Wl2, bl2, xl2, N, C2);
  gemm_bias_kernel<<<g2, 256, 0, stream>>>(hbuf, Wr2, br2, xr2, N, C2);

  attn2_kernel<<<N, 64, 0, stream>>>(xl2, xr2, att2, bias2, indptr, csr, out);
}

// Round 2
// 946.617 us; speedup vs baseline: 1.1200x; 1.1200x over previous
//
#include <hip/hip_runtime.h>
#include <math.h>

#define FIN 128   // input features (layer1 K, layer2 K)
#define F1  128   // H1*C1 = layer1 output width
#define C2  64    // layer2 output width
#define NEG 0.2f  // leaky_relu negative slope

__device__ __forceinline__ float lrelu(float z) { return z > 0.f ? z : NEG * z; }

// ---------------- CSR build (by dst, self-loops appended) ----------------
__global__ void count_deg_kernel(const int* __restrict__ ei, int* __restrict__ cnt,
                                 int E, int N) {
  int e = blockIdx.x * blockDim.x + threadIdx.x;
  if (e >= E + N) return;
  int dst = (e < E) ? ei[E + e] : (e - E);
  atomicAdd(&cnt[dst], 1);
}

// single-block exclusive scan: indptr[v] = sum_{u<v} cnt[u]; cursor gets same.
__global__ __launch_bounds__(1024) void scan_kernel(const int* __restrict__ cnt,
                                                    int* __restrict__ indptr,
                                                    int* __restrict__ cursor, int N) {
  __shared__ int sums[1024];
  int t = threadIdx.x;
  int chunk = (N + 1023) >> 10;
  int b = t * chunk;
  int e = min(N, b + chunk);
  int s = 0;
  for (int i = b; i < e; ++i) s += cnt[i];
  sums[t] = s;
  __syncthreads();
  for (int off = 1; off < 1024; off <<= 1) {
    int val = (t >= off) ? sums[t - off] : 0;
    __syncthreads();
    sums[t] += val;
    __syncthreads();
  }
  int prefix = (t == 0) ? 0 : sums[t - 1];
  for (int i = b; i < e; ++i) {
    int c = cnt[i];          // read before overwrite (cursor may alias cnt)
    indptr[i] = prefix;
    cursor[i] = prefix;
    prefix += c;
  }
  if (t == 1023) indptr[N] = prefix;
}

__global__ void fill_csr_kernel(const int* __restrict__ ei, int* __restrict__ cursor,
                                int* __restrict__ csr, int E, int N) {
  int e = blockIdx.x * blockDim.x + threadIdx.x;
  if (e >= E + N) return;
  int src, dst;
  if (e < E) { src = ei[e]; dst = ei[E + e]; }
  else       { src = e - E; dst = src; }
  int pos = atomicAdd(&cursor[dst], 1);
  csr[pos] = src;
}

// ---------------- fp32 GEMM: O{0,1}[M,Ncols] = A[M,128] @ W{0,1}[128,Ncols] + b{0,1} ----------------
// 64x64 tile, 256 threads, 4x4 per thread; grid.z picks the (W,b,O) set.
__global__ __launch_bounds__(256) void gemm_bias2_kernel(
    const float* __restrict__ A,
    const float* __restrict__ W0, const float* __restrict__ b0, float* __restrict__ O0,
    const float* __restrict__ W1, const float* __restrict__ b1, float* __restrict__ O1,
    int M, int Ncols) {
  const float* W    = blockIdx.z ? W1 : W0;
  const float* bias = blockIdx.z ? b1 : b0;
  float* out        = blockIdx.z ? O1 : O0;
  __shared__ float As[16][68];
  __shared__ float Ws[16][68];
  const int tid = threadIdx.x;
  const int r0 = blockIdx.x * 64;
  const int c0 = blockIdx.y * 64;
  const int tm = tid >> 4;
  const int tc = tid & 15;
  const int la_row = tid >> 2;
  const int la_k4  = (tid & 3) << 2;
  const int lw_k   = tid >> 4;
  const int lw_c4  = (tid & 15) << 2;
  const int arow = min(r0 + la_row, M - 1);
  float acc[4][4] = {{0.f, 0.f, 0.f, 0.f}, {0.f, 0.f, 0.f, 0.f},
                     {0.f, 0.f, 0.f, 0.f}, {0.f, 0.f, 0.f, 0.f}};
  for (int k0 = 0; k0 < FIN; k0 += 16) {
    const float4 av = *(const float4*)(A + (size_t)arow * FIN + k0 + la_k4);
    const float4 wv = *(const float4*)(W + (size_t)(k0 + lw_k) * Ncols + c0 + lw_c4);
    __syncthreads();
    As[la_k4 + 0][la_row] = av.x;
    As[la_k4 + 1][la_row] = av.y;
    As[la_k4 + 2][la_row] = av.z;
    As[la_k4 + 3][la_row] = av.w;
    *(float4*)(&Ws[lw_k][lw_c4]) = wv;
    __syncthreads();
#pragma unroll
    for (int kk = 0; kk < 16; ++kk) {
      const float4 a4 = *(const float4*)(&As[kk][tm << 2]);
      const float4 w4 = *(const float4*)(&Ws[kk][tc << 2]);
      acc[0][0] = fmaf(a4.x, w4.x, acc[0][0]);
      acc[0][1] = fmaf(a4.x, w4.y, acc[0][1]);
      acc[0][2] = fmaf(a4.x, w4.z, acc[0][2]);
      acc[0][3] = fmaf(a4.x, w4.w, acc[0][3]);
      acc[1][0] = fmaf(a4.y, w4.x, acc[1][0]);
      acc[1][1] = fmaf(a4.y, w4.y, acc[1][1]);
      acc[1][2] = fmaf(a4.y, w4.z, acc[1][2]);
      acc[1][3] = fmaf(a4.y, w4.w, acc[1][3]);
      acc[2][0] = fmaf(a4.z, w4.x, acc[2][0]);
      acc[2][1] = fmaf(a4.z, w4.y, acc[2][1]);
      acc[2][2] = fmaf(a4.z, w4.z, acc[2][2]);
      acc[2][3] = fmaf(a4.z, w4.w, acc[2][3]);
      acc[3][0] = fmaf(a4.w, w4.x, acc[3][0]);
      acc[3][1] = fmaf(a4.w, w4.y, acc[3][1]);
      acc[3][2] = fmaf(a4.w, w4.z, acc[3][2]);
      acc[3][3] = fmaf(a4.w, w4.w, acc[3][3]);
    }
  }
  const float4 b4 = *(const float4*)(bias + c0 + (tc << 2));
#pragma unroll
  for (int i = 0; i < 4; ++i) {
    int r = r0 + (tm << 2) + i;
    if (r < M) {
      float4 o;
      o.x = acc[i][0] + b4.x;
      o.y = acc[i][1] + b4.y;
      o.z = acc[i][2] + b4.z;
      o.w = acc[i][3] + b4.w;
      *(float4*)(out + (size_t)r * Ncols + c0 + (tc << 2)) = o;
    }
  }
}

// ---------------- layer 1 fused attention ----------------
// One block of 128 threads per dst node: t -> (head=t>>4, chan=t&15).
// Softmax WITHOUT max-subtraction (scores bounded, fp32 exp range safe):
// l and acc are plain accumulators -> 4-edge batches with full ILP.
__global__ __launch_bounds__(128) void attn1_kernel(
    const float* __restrict__ xl, const float* __restrict__ xr,
    const float* __restrict__ att, const float* __restrict__ bias,
    const int* __restrict__ indptr, const int* __restrict__ csr,
    float* __restrict__ hout) {
  const int v = blockIdx.x;
  const int t = threadIdx.x;
  const float* xlp = xl + t;                 // 32-bit offsets from here
  const float xrv  = xr[(v << 7) + t];
  const float attv = att[t];
  const int beg = indptr[v];
  const int end = indptr[v + 1];
  float l = 0.f, acc = 0.f;
  int e = beg;
  for (; e + 4 <= end; e += 4) {
    const int s0 = csr[e + 0];
    const int s1 = csr[e + 1];
    const int s2 = csr[e + 2];
    const int s3 = csr[e + 3];
    const float x0 = xlp[s0 << 7];
    const float x1 = xlp[s1 << 7];
    const float x2 = xlp[s2 << 7];
    const float x3 = xlp[s3 << 7];
    float t0 = lrelu(x0 + xrv) * attv;
    float t1 = lrelu(x1 + xrv) * attv;
    float t2 = lrelu(x2 + xrv) * attv;
    float t3 = lrelu(x3 + xrv) * attv;
    t0 += __shfl_xor(t0, 1);  t1 += __shfl_xor(t1, 1);
    t2 += __shfl_xor(t2, 1);  t3 += __shfl_xor(t3, 1);
    t0 += __shfl_xor(t0, 2);  t1 += __shfl_xor(t1, 2);
    t2 += __shfl_xor(t2, 2);  t3 += __shfl_xor(t3, 2);
    t0 += __shfl_xor(t0, 4);  t1 += __shfl_xor(t1, 4);
    t2 += __shfl_xor(t2, 4);  t3 += __shfl_xor(t3, 4);
    t0 += __shfl_xor(t0, 8);  t1 += __shfl_xor(t1, 8);
    t2 += __shfl_xor(t2, 8);  t3 += __shfl_xor(t3, 8);
    const float p0 = __expf(t0);
    const float p1 = __expf(t1);
    const float p2 = __expf(t2);
    const float p3 = __expf(t3);
    l += (p0 + p1) + (p2 + p3);
    acc = fmaf(p0, x0, acc);
    acc = fmaf(p1, x1, acc);
    acc = fmaf(p2, x2, acc);
    acc = fmaf(p3, x3, acc);
  }
  for (; e < end; ++e) {
    const int s = csr[e];
    const float xv = xlp[s << 7];
    float tt = lrelu(xv + xrv) * attv;
    tt += __shfl_xor(tt, 1);
    tt += __shfl_xor(tt, 2);
    tt += __shfl_xor(tt, 4);
    tt += __shfl_xor(tt, 8);
    const float p = __expf(tt);
    l += p;
    acc = fmaf(p, xv, acc);
  }
  float res = acc / l + bias[t];
  res = res > 0.f ? res : expm1f(res);        // ELU
  hout[(v << 7) + t] = res;
}

// ---------------- layer 2 fused attention: 1 head x 64 chans, one wave per node ----------------
__global__ __launch_bounds__(64) void attn2_kernel(
    const float* __restrict__ xl, const float* __restrict__ xr,
    const float* __restrict__ att, const float* __restrict__ bias,
    const int* __restrict__ indptr, const int* __restrict__ csr,
    float* __restrict__ out) {
  const int v = blockIdx.x;
  const int t = threadIdx.x;
  const float* xlp = xl + t;
  const float xrv  = xr[(v << 6) + t];
  const float attv = att[t];
  const int beg = indptr[v];
  const int end = indptr[v + 1];
  float l = 0.f, acc = 0.f;
  int e = beg;
  for (; e + 4 <= end; e += 4) {
    const int s0 = csr[e + 0];
    const int s1 = csr[e + 1];
    const int s2 = csr[e + 2];
    const int s3 = csr[e + 3];
    const float x0 = xlp[s0 << 6];
    const float x1 = xlp[s1 << 6];
    const float x2 = xlp[s2 << 6];
    const float x3 = xlp[s3 << 6];
    float t0 = lrelu(x0 + xrv) * attv;
    float t1 = lrelu(x1 + xrv) * attv;
    float t2 = lrelu(x2 + xrv) * attv;
    float t3 = lrelu(x3 + xrv) * attv;
    t0 += __shfl_xor(t0, 1);  t1 += __shfl_xor(t1, 1);
    t2 += __shfl_xor(t2, 1);  t3 += __shfl_xor(t3, 1);
    t0 += __shfl_xor(t0, 2);  t1 += __shfl_xor(t1, 2);
    t2 += __shfl_xor(t2, 2);  t3 += __shfl_xor(t3, 2);
    t0 += __shfl_xor(t0, 4);  t1 += __shfl_xor(t1, 4);
    t2 += __shfl_xor(t2, 4);  t3 += __shfl_xor(t3, 4);
    t0 += __shfl_xor(t0, 8);  t1 += __shfl_xor(t1, 8);
    t2 += __shfl_xor(t2, 8);  t3 += __shfl_xor(t3, 8);
    t0 += __shfl_xor(t0, 16); t1 += __shfl_xor(t1, 16);
    t2 += __shfl_xor(t2, 16); t3 += __shfl_xor(t3, 16);
    t0 += __shfl_xor(t0, 32); t1 += __shfl_xor(t1, 32);
    t2 += __shfl_xor(t2, 32); t3 += __shfl_xor(t3, 32);
    const float p0 = __expf(t0);
    const float p1 = __expf(t1);
    const float p2 = __expf(t2);
    const float p3 = __expf(t3);
    l += (p0 + p1) + (p2 + p3);
    acc = fmaf(p0, x0, acc);
    acc = fmaf(p1, x1, acc);
    acc = fmaf(p2, x2, acc);
    acc = fmaf(p3, x3, acc);
  }
  for (; e < end; ++e) {
    const int s = csr[e];
    const float xv = xlp[s << 6];
    float tt = lrelu(xv + xrv) * attv;
    tt += __shfl_xor(tt, 1);
    tt += __shfl_xor(tt, 2);
    tt += __shfl_xor(tt, 4);
    tt += __shfl_xor(tt, 8);
    tt += __shfl_xor(tt, 16);
    tt += __shfl_xor(tt, 32);
    const float p = __expf(tt);
    l += p;
    acc = fmaf(p, xv, acc);
  }
  out[(v << 6) + t] = acc / l + bias[t];
}

extern "C" void kernel_launch(void* const* d_in, const int* in_sizes, int n_in,
                              void* d_out, int out_size, void* d_ws, size_t ws_size,
                              hipStream_t stream) {
  const float* x     = (const float*)d_in[0];
  const int*   ei    = (const int*)d_in[1];
  const float* Wl1   = (const float*)d_in[2];
  const float* bl1   = (const float*)d_in[3];
  const float* Wr1   = (const float*)d_in[4];
  const float* br1   = (const float*)d_in[5];
  const float* att1  = (const float*)d_in[6];
  const float* bias1 = (const float*)d_in[7];
  const float* Wl2   = (const float*)d_in[8];
  const float* bl2   = (const float*)d_in[9];
  const float* Wr2   = (const float*)d_in[10];
  const float* br2   = (const float*)d_in[11];
  const float* att2  = (const float*)d_in[12];
  const float* bias2 = (const float*)d_in[13];

  const int N  = in_sizes[0] / FIN;   // 100000
  const int E  = in_sizes[1] / 2;     // 1600000
  const int ET = E + N;

  float* xl1  = (float*)d_ws;                  // N*128
  float* xr1  = xl1 + (size_t)N * F1;          // N*128
  float* hbuf = xr1 + (size_t)N * F1;          // N*128
  int* indptr = (int*)(hbuf + (size_t)N * F1); // N+1
  int* cursor = indptr + (N + 1);              // N (doubles as cnt)
  int* csr    = cursor + N;                    // ET
  float* xl2  = xl1;                           // reuse layer1 region
  float* xr2  = xl1 + (size_t)N * C2;
  float* out  = (float*)d_out;

  const int tb = 256;
  const int eblocks = (ET + tb - 1) / tb;

  hipMemsetAsync(cursor, 0, (size_t)N * sizeof(int), stream);
  count_deg_kernel<<<eblocks, tb, 0, stream>>>(ei, cursor, E, N);
  scan_kernel<<<1, 1024, 0, stream>>>(cursor, indptr, cursor, N);
  fill_csr_kernel<<<eblocks, tb, 0, stream>>>(ei, cursor, csr, E, N);

  dim3 g1((N + 63) / 64, F1 / 64, 2);
  gemm_bias2_kernel<<<g1, 256, 0, stream>>>(x, Wl1, bl1, xl1, Wr1, br1, xr1, N, F1);

  attn1_kernel<<<N, 128, 0, stream>>>(xl1, xr1, att1, bias1, indptr, csr, hbuf);

  dim3 g2((N + 63) / 64, C2 / 64, 2);
  gemm_bias2_kernel<<<g2, 256, 0, stream>>>(hbuf, Wl2, bl2, xl2, Wr2, br2, xr2, N, C2);

  attn2_kernel<<<N, 64, 0, stream>>>(xl2, xr2, att2, bias2, indptr, csr, out);
}

// Round 3
// 680.682 us; speedup vs baseline: 1.5576x; 1.3907x over previous
//
#include <hip/hip_runtime.h>
#include <math.h>

#define FIN 128   // input features (layer1 K, layer2 K)
#define F1  128   // H1*C1 = layer1 output width
#define C2  64    // layer2 output width
#define NEG 0.2f  // leaky_relu negative slope

__device__ __forceinline__ float lrelu(float z) { return z > 0.f ? z : NEG * z; }

// ---------------- CSR build (by dst, self-loops appended) ----------------
__global__ void count_deg_kernel(const int* __restrict__ ei, int* __restrict__ cnt,
                                 int E, int N) {
  int e = blockIdx.x * blockDim.x + threadIdx.x;
  if (e >= E + N) return;
  int dst = (e < E) ? ei[E + e] : (e - E);
  atomicAdd(&cnt[dst], 1);
}

// ---- hierarchical exclusive scan: 1024 elements per block, 256 thr x int4 ----
__global__ __launch_bounds__(256) void scan_partial_kernel(
    const int* __restrict__ cnt, int* __restrict__ indptr,
    int* __restrict__ bsum, int N) {
  __shared__ int sh[256];
  const int t = threadIdx.x;
  const int base = blockIdx.x * 1024 + t * 4;
  int v0 = 0, v1 = 0, v2 = 0, v3 = 0;
  if (base + 3 < N) {
    int4 q = *(const int4*)(cnt + base);
    v0 = q.x; v1 = q.y; v2 = q.z; v3 = q.w;
  } else {
    if (base + 0 < N) v0 = cnt[base + 0];
    if (base + 1 < N) v1 = cnt[base + 1];
    if (base + 2 < N) v2 = cnt[base + 2];
  }
  const int s = v0 + v1 + v2 + v3;
  sh[t] = s;
  __syncthreads();
  for (int off = 1; off < 256; off <<= 1) {
    int val = (t >= off) ? sh[t - off] : 0;
    __syncthreads();
    sh[t] += val;
    __syncthreads();
  }
  const int excl = sh[t] - s;   // exclusive within block
  if (t == 255) bsum[blockIdx.x] = sh[255];
  if (base + 0 < N) indptr[base + 0] = excl;
  if (base + 1 < N) indptr[base + 1] = excl + v0;
  if (base + 2 < N) indptr[base + 2] = excl + v0 + v1;
  if (base + 3 < N) indptr[base + 3] = excl + v0 + v1 + v2;
}

// single block scans the per-block totals (covers NB <= 1024, i.e. N <= 1M)
__global__ __launch_bounds__(1024) void scan_bsum_kernel(
    int* __restrict__ bsum, int* __restrict__ indptr, int NB, int N) {
  __shared__ int sh[1024];
  const int t = threadIdx.x;
  const int v = (t < NB) ? bsum[t] : 0;
  sh[t] = v;
  __syncthreads();
  for (int off = 1; off < 1024; off <<= 1) {
    int val = (t >= off) ? sh[t - off] : 0;
    __syncthreads();
    sh[t] += val;
    __syncthreads();
  }
  if (t < NB) bsum[t] = sh[t] - v;  // exclusive block offsets
  if (t == 1023) indptr[N] = sh[1023];
}

__global__ __launch_bounds__(256) void scan_add_kernel(
    int* __restrict__ indptr, int* __restrict__ cursor,
    const int* __restrict__ bsum, int N) {
  const int off = bsum[blockIdx.x];
  const int base = blockIdx.x * 1024 + threadIdx.x * 4;
  if (base + 3 < N) {
    int4 q = *(const int4*)(indptr + base);
    q.x += off; q.y += off; q.z += off; q.w += off;
    *(int4*)(indptr + base) = q;
    *(int4*)(cursor + base) = q;
  } else {
#pragma unroll
    for (int j = 0; j < 4; ++j) {
      int i = base + j;
      if (i < N) {
        int val = indptr[i] + off;
        indptr[i] = val;
        cursor[i] = val;
      }
    }
  }
}

__global__ void fill_csr_kernel(const int* __restrict__ ei, int* __restrict__ cursor,
                                int* __restrict__ csr, int E, int N) {
  int e = blockIdx.x * blockDim.x + threadIdx.x;
  if (e >= E + N) return;
  int src, dst;
  if (e < E) { src = ei[e]; dst = ei[E + e]; }
  else       { src = e - E; dst = src; }
  int pos = atomicAdd(&cursor[dst], 1);
  csr[pos] = src;
}

// ---------------- fp32 GEMM: O{0,1}[M,Ncols] = A[M,128] @ W{0,1}[128,Ncols] + b{0,1} ----------------
// 64x64 tile, 256 threads, 4x4 per thread; grid.z picks the (W,b,O) set.
__global__ __launch_bounds__(256) void gemm_bias2_kernel(
    const float* __restrict__ A,
    const float* __restrict__ W0, const float* __restrict__ b0, float* __restrict__ O0,
    const float* __restrict__ W1, const float* __restrict__ b1, float* __restrict__ O1,
    int M, int Ncols) {
  const float* W    = blockIdx.z ? W1 : W0;
  const float* bias = blockIdx.z ? b1 : b0;
  float* out        = blockIdx.z ? O1 : O0;
  __shared__ float As[16][68];
  __shared__ float Ws[16][68];
  const int tid = threadIdx.x;
  const int r0 = blockIdx.x * 64;
  const int c0 = blockIdx.y * 64;
  const int tm = tid >> 4;
  const int tc = tid & 15;
  const int la_row = tid >> 2;
  const int la_k4  = (tid & 3) << 2;
  const int lw_k   = tid >> 4;
  const int lw_c4  = (tid & 15) << 2;
  const int arow = min(r0 + la_row, M - 1);
  float acc[4][4] = {{0.f, 0.f, 0.f, 0.f}, {0.f, 0.f, 0.f, 0.f},
                     {0.f, 0.f, 0.f, 0.f}, {0.f, 0.f, 0.f, 0.f}};
  for (int k0 = 0; k0 < FIN; k0 += 16) {
    const float4 av = *(const float4*)(A + (size_t)arow * FIN + k0 + la_k4);
    const float4 wv = *(const float4*)(W + (size_t)(k0 + lw_k) * Ncols + c0 + lw_c4);
    __syncthreads();
    As[la_k4 + 0][la_row] = av.x;
    As[la_k4 + 1][la_row] = av.y;
    As[la_k4 + 2][la_row] = av.z;
    As[la_k4 + 3][la_row] = av.w;
    *(float4*)(&Ws[lw_k][lw_c4]) = wv;
    __syncthreads();
#pragma unroll
    for (int kk = 0; kk < 16; ++kk) {
      const float4 a4 = *(const float4*)(&As[kk][tm << 2]);
      const float4 w4 = *(const float4*)(&Ws[kk][tc << 2]);
      acc[0][0] = fmaf(a4.x, w4.x, acc[0][0]);
      acc[0][1] = fmaf(a4.x, w4.y, acc[0][1]);
      acc[0][2] = fmaf(a4.x, w4.z, acc[0][2]);
      acc[0][3] = fmaf(a4.x, w4.w, acc[0][3]);
      acc[1][0] = fmaf(a4.y, w4.x, acc[1][0]);
      acc[1][1] = fmaf(a4.y, w4.y, acc[1][1]);
      acc[1][2] = fmaf(a4.y, w4.z, acc[1][2]);
      acc[1][3] = fmaf(a4.y, w4.w, acc[1][3]);
      acc[2][0] = fmaf(a4.z, w4.x, acc[2][0]);
      acc[2][1] = fmaf(a4.z, w4.y, acc[2][1]);
      acc[2][2] = fmaf(a4.z, w4.z, acc[2][2]);
      acc[2][3] = fmaf(a4.z, w4.w, acc[2][3]);
      acc[3][0] = fmaf(a4.w, w4.x, acc[3][0]);
      acc[3][1] = fmaf(a4.w, w4.y, acc[3][1]);
      acc[3][2] = fmaf(a4.w, w4.z, acc[3][2]);
      acc[3][3] = fmaf(a4.w, w4.w, acc[3][3]);
    }
  }
  const float4 b4 = *(const float4*)(bias + c0 + (tc << 2));
#pragma unroll
  for (int i = 0; i < 4; ++i) {
    int r = r0 + (tm << 2) + i;
    if (r < M) {
      float4 o;
      o.x = acc[i][0] + b4.x;
      o.y = acc[i][1] + b4.y;
      o.z = acc[i][2] + b4.z;
      o.w = acc[i][3] + b4.w;
      *(float4*)(out + (size_t)r * Ncols + c0 + (tc << 2)) = o;
    }
  }
}

// ---------------- layer 1 fused attention ----------------
// One block of 128 threads per dst node: t -> (head=t>>4, chan=t&15).
// Softmax WITHOUT max-subtraction (scores bounded, fp32 exp range safe):
// l and acc are plain accumulators -> 4-edge batches with full ILP.
__global__ __launch_bounds__(128) void attn1_kernel(
    const float* __restrict__ xl, const float* __restrict__ xr,
    const float* __restrict__ att, const float* __restrict__ bias,
    const int* __restrict__ indptr, const int* __restrict__ csr,
    float* __restrict__ hout) {
  const int v = blockIdx.x;
  const int t = threadIdx.x;
  const float* xlp = xl + t;                 // 32-bit offsets from here
  const float xrv  = xr[(v << 7) + t];
  const float attv = att[t];
  const int beg = indptr[v];
  const int end = indptr[v + 1];
  float l = 0.f, acc = 0.f;
  int e = beg;
  for (; e + 4 <= end; e += 4) {
    const int s0 = csr[e + 0];
    const int s1 = csr[e + 1];
    const int s2 = csr[e + 2];
    const int s3 = csr[e + 3];
    const float x0 = xlp[s0 << 7];
    const float x1 = xlp[s1 << 7];
    const float x2 = xlp[s2 << 7];
    const float x3 = xlp[s3 << 7];
    float t0 = lrelu(x0 + xrv) * attv;
    float t1 = lrelu(x1 + xrv) * attv;
    float t2 = lrelu(x2 + xrv) * attv;
    float t3 = lrelu(x3 + xrv) * attv;
    t0 += __shfl_xor(t0, 1);  t1 += __shfl_xor(t1, 1);
    t2 += __shfl_xor(t2, 1);  t3 += __shfl_xor(t3, 1);
    t0 += __shfl_xor(t0, 2);  t1 += __shfl_xor(t1, 2);
    t2 += __shfl_xor(t2, 2);  t3 += __shfl_xor(t3, 2);
    t0 += __shfl_xor(t0, 4);  t1 += __shfl_xor(t1, 4);
    t2 += __shfl_xor(t2, 4);  t3 += __shfl_xor(t3, 4);
    t0 += __shfl_xor(t0, 8);  t1 += __shfl_xor(t1, 8);
    t2 += __shfl_xor(t2, 8);  t3 += __shfl_xor(t3, 8);
    const float p0 = __expf(t0);
    const float p1 = __expf(t1);
    const float p2 = __expf(t2);
    const float p3 = __expf(t3);
    l += (p0 + p1) + (p2 + p3);
    acc = fmaf(p0, x0, acc);
    acc = fmaf(p1, x1, acc);
    acc = fmaf(p2, x2, acc);
    acc = fmaf(p3, x3, acc);
  }
  for (; e < end; ++e) {
    const int s = csr[e];
    const float xv = xlp[s << 7];
    float tt = lrelu(xv + xrv) * attv;
    tt += __shfl_xor(tt, 1);
    tt += __shfl_xor(tt, 2);
    tt += __shfl_xor(tt, 4);
    tt += __shfl_xor(tt, 8);
    const float p = __expf(tt);
    l += p;
    acc = fmaf(p, xv, acc);
  }
  float res = acc / l + bias[t];
  res = res > 0.f ? res : expm1f(res);        // ELU
  hout[(v << 7) + t] = res;
}

// ---------------- layer 2 fused attention: 1 head x 64 chans, one wave per node ----------------
__global__ __launch_bounds__(64) void attn2_kernel(
    const float* __restrict__ xl, const float* __restrict__ xr,
    const float* __restrict__ att, const float* __restrict__ bias,
    const int* __restrict__ indptr, const int* __restrict__ csr,
    float* __restrict__ out) {
  const int v = blockIdx.x;
  const int t = threadIdx.x;
  const float* xlp = xl + t;
  const float xrv  = xr[(v << 6) + t];
  const float attv = att[t];
  const int beg = indptr[v];
  const int end = indptr[v + 1];
  float l = 0.f, acc = 0.f;
  int e = beg;
  for (; e + 4 <= end; e += 4) {
    const int s0 = csr[e + 0];
    const int s1 = csr[e + 1];
    const int s2 = csr[e + 2];
    const int s3 = csr[e + 3];
    const float x0 = xlp[s0 << 6];
    const float x1 = xlp[s1 << 6];
    const float x2 = xlp[s2 << 6];
    const float x3 = xlp[s3 << 6];
    float t0 = lrelu(x0 + xrv) * attv;
    float t1 = lrelu(x1 + xrv) * attv;
    float t2 = lrelu(x2 + xrv) * attv;
    float t3 = lrelu(x3 + xrv) * attv;
    t0 += __shfl_xor(t0, 1);  t1 += __shfl_xor(t1, 1);
    t2 += __shfl_xor(t2, 1);  t3 += __shfl_xor(t3, 1);
    t0 += __shfl_xor(t0, 2);  t1 += __shfl_xor(t1, 2);
    t2 += __shfl_xor(t2, 2);  t3 += __shfl_xor(t3, 2);
    t0 += __shfl_xor(t0, 4);  t1 += __shfl_xor(t1, 4);
    t2 += __shfl_xor(t2, 4);  t3 += __shfl_xor(t3, 4);
    t0 += __shfl_xor(t0, 8);  t1 += __shfl_xor(t1, 8);
    t2 += __shfl_xor(t2, 8);  t3 += __shfl_xor(t3, 8);
    t0 += __shfl_xor(t0, 16); t1 += __shfl_xor(t1, 16);
    t2 += __shfl_xor(t2, 16); t3 += __shfl_xor(t3, 16);
    t0 += __shfl_xor(t0, 32); t1 += __shfl_xor(t1, 32);
    t2 += __shfl_xor(t2, 32); t3 += __shfl_xor(t3, 32);
    const float p0 = __expf(t0);
    const float p1 = __expf(t1);
    const float p2 = __expf(t2);
    const float p3 = __expf(t3);
    l += (p0 + p1) + (p2 + p3);
    acc = fmaf(p0, x0, acc);
    acc = fmaf(p1, x1, acc);
    acc = fmaf(p2, x2, acc);
    acc = fmaf(p3, x3, acc);
  }
  for (; e < end; ++e) {
    const int s = csr[e];
    const float xv = xlp[s << 6];
    float tt = lrelu(xv + xrv) * attv;
    tt += __shfl_xor(tt, 1);
    tt += __shfl_xor(tt, 2);
    tt += __shfl_xor(tt, 4);
    tt += __shfl_xor(tt, 8);
    tt += __shfl_xor(tt, 16);
    tt += __shfl_xor(tt, 32);
    const float p = __expf(tt);
    l += p;
    acc = fmaf(p, xv, acc);
  }
  out[(v << 6) + t] = acc / l + bias[t];
}

extern "C" void kernel_launch(void* const* d_in, const int* in_sizes, int n_in,
                              void* d_out, int out_size, void* d_ws, size_t ws_size,
                              hipStream_t stream) {
  const float* x     = (const float*)d_in[0];
  const int*   ei    = (const int*)d_in[1];
  const float* Wl1   = (const float*)d_in[2];
  const float* bl1   = (const float*)d_in[3];
  const float* Wr1   = (const float*)d_in[4];
  const float* br1   = (const float*)d_in[5];
  const float* att1  = (const float*)d_in[6];
  const float* bias1 = (const float*)d_in[7];
  const float* Wl2   = (const float*)d_in[8];
  const float* bl2   = (const float*)d_in[9];
  const float* Wr2   = (const float*)d_in[10];
  const float* br2   = (const float*)d_in[11];
  const float* att2  = (const float*)d_in[12];
  const float* bias2 = (const float*)d_in[13];

  const int N  = in_sizes[0] / FIN;   // 100000
  const int E  = in_sizes[1] / 2;     // 1600000
  const int ET = E + N;

  float* xl1  = (float*)d_ws;                  // N*128
  float* xr1  = xl1 + (size_t)N * F1;          // N*128
  float* hbuf = xr1 + (size_t)N * F1;          // N*128
  int* indptr = (int*)(hbuf + (size_t)N * F1); // N+1
  int* cursor = indptr + (N + 1);              // N (doubles as cnt)
  int* csr    = cursor + N;                    // ET
  int* bsum   = csr + ET;                      // (N+1023)/1024
  float* xl2  = xl1;                           // reuse layer1 region
  float* xr2  = xl1 + (size_t)N * C2;
  float* out  = (float*)d_out;

  const int tb = 256;
  const int eblocks = (ET + tb - 1) / tb;
  const int NB = (N + 1023) / 1024;            // 98 for N=100000 (<=1024 supported)

  hipMemsetAsync(cursor, 0, (size_t)N * sizeof(int), stream);
  count_deg_kernel<<<eblocks, tb, 0, stream>>>(ei, cursor, E, N);
  scan_partial_kernel<<<NB, 256, 0, stream>>>(cursor, indptr, bsum, N);
  scan_bsum_kernel<<<1, 1024, 0, stream>>>(bsum, indptr, NB, N);
  scan_add_kernel<<<NB, 256, 0, stream>>>(indptr, cursor, bsum, N);
  fill_csr_kernel<<<eblocks, tb, 0, stream>>>(ei, cursor, csr, E, N);

  dim3 g1((N + 63) / 64, F1 / 64, 2);
  gemm_bias2_kernel<<<g1, 256, 0, stream>>>(x, Wl1, bl1, xl1, Wr1, br1, xr1, N, F1);

  attn1_kernel<<<N, 128, 0, stream>>>(xl1, xr1, att1, bias1, indptr, csr, hbuf);

  dim3 g2((N + 63) / 64, C2 / 64, 2);
  gemm_bias2_kernel<<<g2, 256, 0, stream>>>(hbuf, Wl2, bl2, xl2, Wr2, br2, xr2, N, C2);

  attn2_kernel<<<N, 64, 0, stream>>>(xl2, xr2, att2, bias2, indptr, csr, out);
}

// Round 4
// 641.337 us; speedup vs baseline: 1.6531x; 1.0613x over previous
//
#include <hip/hip_runtime.h>
#include <math.h>

#define FIN 128   // input features (layer1 K, layer2 K)
#define F1  128   // H1*C1 = layer1 output width
#define C2  64    // layer2 output width
#define NEG 0.2f  // leaky_relu negative slope

__device__ __forceinline__ float lrelu(float z) { return fmaxf(z, NEG * z); }

// ---------------- CSR build (by dst, self-loops appended) ----------------
__global__ void count_deg_kernel(const int* __restrict__ ei, int* __restrict__ cnt,
                                 int E, int N) {
  int e = blockIdx.x * blockDim.x + threadIdx.x;
  if (e >= E + N) return;
  int dst = (e < E) ? ei[E + e] : (e - E);
  atomicAdd(&cnt[dst], 1);
}

// ---- hierarchical exclusive scan: 1024 elements per block, 256 thr x int4 ----
__global__ __launch_bounds__(256) void scan_partial_kernel(
    const int* __restrict__ cnt, int* __restrict__ indptr,
    int* __restrict__ bsum, int N) {
  __shared__ int sh[256];
  const int t = threadIdx.x;
  const int base = blockIdx.x * 1024 + t * 4;
  int v0 = 0, v1 = 0, v2 = 0, v3 = 0;
  if (base + 3 < N) {
    int4 q = *(const int4*)(cnt + base);
    v0 = q.x; v1 = q.y; v2 = q.z; v3 = q.w;
  } else {
    if (base + 0 < N) v0 = cnt[base + 0];
    if (base + 1 < N) v1 = cnt[base + 1];
    if (base + 2 < N) v2 = cnt[base + 2];
  }
  const int s = v0 + v1 + v2 + v3;
  sh[t] = s;
  __syncthreads();
  for (int off = 1; off < 256; off <<= 1) {
    int val = (t >= off) ? sh[t - off] : 0;
    __syncthreads();
    sh[t] += val;
    __syncthreads();
  }
  const int excl = sh[t] - s;   // exclusive within block
  if (t == 255) bsum[blockIdx.x] = sh[255];
  if (base + 0 < N) indptr[base + 0] = excl;
  if (base + 1 < N) indptr[base + 1] = excl + v0;
  if (base + 2 < N) indptr[base + 2] = excl + v0 + v1;
  if (base + 3 < N) indptr[base + 3] = excl + v0 + v1 + v2;
}

// single block scans the per-block totals (covers NB <= 1024, i.e. N <= 1M)
__global__ __launch_bounds__(1024) void scan_bsum_kernel(
    int* __restrict__ bsum, int* __restrict__ indptr, int NB, int N) {
  __shared__ int sh[1024];
  const int t = threadIdx.x;
  const int v = (t < NB) ? bsum[t] : 0;
  sh[t] = v;
  __syncthreads();
  for (int off = 1; off < 1024; off <<= 1) {
    int val = (t >= off) ? sh[t - off] : 0;
    __syncthreads();
    sh[t] += val;
    __syncthreads();
  }
  if (t < NB) bsum[t] = sh[t] - v;  // exclusive block offsets
  if (t == 1023) indptr[N] = sh[1023];
}

__global__ __launch_bounds__(256) void scan_add_kernel(
    int* __restrict__ indptr, int* __restrict__ cursor,
    const int* __restrict__ bsum, int N) {
  const int off = bsum[blockIdx.x];
  const int base = blockIdx.x * 1024 + threadIdx.x * 4;
  if (base + 3 < N) {
    int4 q = *(const int4*)(indptr + base);
    q.x += off; q.y += off; q.z += off; q.w += off;
    *(int4*)(indptr + base) = q;
    *(int4*)(cursor + base) = q;
  } else {
#pragma unroll
    for (int j = 0; j < 4; ++j) {
      int i = base + j;
      if (i < N) {
        int val = indptr[i] + off;
        indptr[i] = val;
        cursor[i] = val;
      }
    }
  }
}

__global__ void fill_csr_kernel(const int* __restrict__ ei, int* __restrict__ cursor,
                                int* __restrict__ csr, int E, int N) {
  int e = blockIdx.x * blockDim.x + threadIdx.x;
  if (e >= E + N) return;
  int src, dst;
  if (e < E) { src = ei[e]; dst = ei[E + e]; }
  else       { src = e - E; dst = src; }
  int pos = atomicAdd(&cursor[dst], 1);
  csr[pos] = src;
}

// ---------------- fp32 GEMM: O{0,1}[M,Ncols] = A[M,128] @ W{0,1}[128,Ncols] + b{0,1} ----------------
__global__ __launch_bounds__(256) void gemm_bias2_kernel(
    const float* __restrict__ A,
    const float* __restrict__ W0, const float* __restrict__ b0, float* __restrict__ O0,
    const float* __restrict__ W1, const float* __restrict__ b1, float* __restrict__ O1,
    int M, int Ncols) {
  const float* W    = blockIdx.z ? W1 : W0;
  const float* bias = blockIdx.z ? b1 : b0;
  float* out        = blockIdx.z ? O1 : O0;
  __shared__ float As[16][68];
  __shared__ float Ws[16][68];
  const int tid = threadIdx.x;
  const int r0 = blockIdx.x * 64;
  const int c0 = blockIdx.y * 64;
  const int tm = tid >> 4;
  const int tc = tid & 15;
  const int la_row = tid >> 2;
  const int la_k4  = (tid & 3) << 2;
  const int lw_k   = tid >> 4;
  const int lw_c4  = (tid & 15) << 2;
  const int arow = min(r0 + la_row, M - 1);
  float acc[4][4] = {{0.f, 0.f, 0.f, 0.f}, {0.f, 0.f, 0.f, 0.f},
                     {0.f, 0.f, 0.f, 0.f}, {0.f, 0.f, 0.f, 0.f}};
  for (int k0 = 0; k0 < FIN; k0 += 16) {
    const float4 av = *(const float4*)(A + (size_t)arow * FIN + k0 + la_k4);
    const float4 wv = *(const float4*)(W + (size_t)(k0 + lw_k) * Ncols + c0 + lw_c4);
    __syncthreads();
    As[la_k4 + 0][la_row] = av.x;
    As[la_k4 + 1][la_row] = av.y;
    As[la_k4 + 2][la_row] = av.z;
    As[la_k4 + 3][la_row] = av.w;
    *(float4*)(&Ws[lw_k][lw_c4]) = wv;
    __syncthreads();
#pragma unroll
    for (int kk = 0; kk < 16; ++kk) {
      const float4 a4 = *(const float4*)(&As[kk][tm << 2]);
      const float4 w4 = *(const float4*)(&Ws[kk][tc << 2]);
      acc[0][0] = fmaf(a4.x, w4.x, acc[0][0]);
      acc[0][1] = fmaf(a4.x, w4.y, acc[0][1]);
      acc[0][2] = fmaf(a4.x, w4.z, acc[0][2]);
      acc[0][3] = fmaf(a4.x, w4.w, acc[0][3]);
      acc[1][0] = fmaf(a4.y, w4.x, acc[1][0]);
      acc[1][1] = fmaf(a4.y, w4.y, acc[1][1]);
      acc[1][2] = fmaf(a4.y, w4.z, acc[1][2]);
      acc[1][3] = fmaf(a4.y, w4.w, acc[1][3]);
      acc[2][0] = fmaf(a4.z, w4.x, acc[2][0]);
      acc[2][1] = fmaf(a4.z, w4.y, acc[2][1]);
      acc[2][2] = fmaf(a4.z, w4.z, acc[2][2]);
      acc[2][3] = fmaf(a4.z, w4.w, acc[2][3]);
      acc[3][0] = fmaf(a4.w, w4.x, acc[3][0]);
      acc[3][1] = fmaf(a4.w, w4.y, acc[3][1]);
      acc[3][2] = fmaf(a4.w, w4.z, acc[3][2]);
      acc[3][3] = fmaf(a4.w, w4.w, acc[3][3]);
    }
  }
  const float4 b4 = *(const float4*)(bias + c0 + (tc << 2));
#pragma unroll
  for (int i = 0; i < 4; ++i) {
    int r = r0 + (tm << 2) + i;
    if (r < M) {
      float4 o;
      o.x = acc[i][0] + b4.x;
      o.y = acc[i][1] + b4.y;
      o.z = acc[i][2] + b4.z;
      o.w = acc[i][3] + b4.w;
      *(float4*)(out + (size_t)r * Ncols + c0 + (tc << 2)) = o;
    }
  }
}

// ---------------- layer 1 fused attention, float4 channels ----------------
// 256 threads = 8 nodes x 32 lanes; lane owns chans [4*lane .. 4*lane+3].
// Head = 4 consecutive lanes -> score reduce = 2-stage butterfly.
// Softmax without max-subtraction (scores bounded; fp32 exp range safe).
__global__ __launch_bounds__(256) void attn1_kernel(
    const float* __restrict__ xl, const float* __restrict__ xr,
    const float* __restrict__ att, const float* __restrict__ bias,
    const int* __restrict__ indptr, const int* __restrict__ csr,
    float* __restrict__ hout, int N) {
  const int lane = threadIdx.x & 31;
  const int v = blockIdx.x * 8 + (threadIdx.x >> 5);
  if (v >= N) return;
  const int c4 = lane << 2;
  const float* xlp = xl + c4;                  // + s*128 per edge
  const float4 xr4 = *(const float4*)(xr + (v << 7) + c4);
  const float4 a4  = *(const float4*)(att + c4);
  const int beg = indptr[v];
  const int end = indptr[v + 1];
  float l = 0.f;
  float4 acc = {0.f, 0.f, 0.f, 0.f};
  int e = beg;
  for (; e + 4 <= end; e += 4) {
    const int s0 = csr[e + 0];
    const int s1 = csr[e + 1];
    const int s2 = csr[e + 2];
    const int s3 = csr[e + 3];
    const float4 x0 = *(const float4*)(xlp + (s0 << 7));
    const float4 x1 = *(const float4*)(xlp + (s1 << 7));
    const float4 x2 = *(const float4*)(xlp + (s2 << 7));
    const float4 x3 = *(const float4*)(xlp + (s3 << 7));
    float t0 = lrelu(x0.x + xr4.x) * a4.x + lrelu(x0.y + xr4.y) * a4.y
             + lrelu(x0.z + xr4.z) * a4.z + lrelu(x0.w + xr4.w) * a4.w;
    float t1 = lrelu(x1.x + xr4.x) * a4.x + lrelu(x1.y + xr4.y) * a4.y
             + lrelu(x1.z + xr4.z) * a4.z + lrelu(x1.w + xr4.w) * a4.w;
    float t2 = lrelu(x2.x + xr4.x) * a4.x + lrelu(x2.y + xr4.y) * a4.y
             + lrelu(x2.z + xr4.z) * a4.z + lrelu(x2.w + xr4.w) * a4.w;
    float t3 = lrelu(x3.x + xr4.x) * a4.x + lrelu(x3.y + xr4.y) * a4.y
             + lrelu(x3.z + xr4.z) * a4.z + lrelu(x3.w + xr4.w) * a4.w;
    t0 += __shfl_xor(t0, 1);  t1 += __shfl_xor(t1, 1);
    t2 += __shfl_xor(t2, 1);  t3 += __shfl_xor(t3, 1);
    t0 += __shfl_xor(t0, 2);  t1 += __shfl_xor(t1, 2);
    t2 += __shfl_xor(t2, 2);  t3 += __shfl_xor(t3, 2);
    const float p0 = __expf(t0);
    const float p1 = __expf(t1);
    const float p2 = __expf(t2);
    const float p3 = __expf(t3);
    l += (p0 + p1) + (p2 + p3);
    acc.x = fmaf(p0, x0.x, acc.x); acc.y = fmaf(p0, x0.y, acc.y);
    acc.z = fmaf(p0, x0.z, acc.z); acc.w = fmaf(p0, x0.w, acc.w);
    acc.x = fmaf(p1, x1.x, acc.x); acc.y = fmaf(p1, x1.y, acc.y);
    acc.z = fmaf(p1, x1.z, acc.z); acc.w = fmaf(p1, x1.w, acc.w);
    acc.x = fmaf(p2, x2.x, acc.x); acc.y = fmaf(p2, x2.y, acc.y);
    acc.z = fmaf(p2, x2.z, acc.z); acc.w = fmaf(p2, x2.w, acc.w);
    acc.x = fmaf(p3, x3.x, acc.x); acc.y = fmaf(p3, x3.y, acc.y);
    acc.z = fmaf(p3, x3.z, acc.z); acc.w = fmaf(p3, x3.w, acc.w);
  }
  for (; e < end; ++e) {
    const int s = csr[e];
    const float4 xv = *(const float4*)(xlp + (s << 7));
    float tt = lrelu(xv.x + xr4.x) * a4.x + lrelu(xv.y + xr4.y) * a4.y
             + lrelu(xv.z + xr4.z) * a4.z + lrelu(xv.w + xr4.w) * a4.w;
    tt += __shfl_xor(tt, 1);
    tt += __shfl_xor(tt, 2);
    const float p = __expf(tt);
    l += p;
    acc.x = fmaf(p, xv.x, acc.x); acc.y = fmaf(p, xv.y, acc.y);
    acc.z = fmaf(p, xv.z, acc.z); acc.w = fmaf(p, xv.w, acc.w);
  }
  const float rl = 1.f / l;
  const float4 b4 = *(const float4*)(bias + c4);
  float4 res;
  res.x = fmaf(acc.x, rl, b4.x);
  res.y = fmaf(acc.y, rl, b4.y);
  res.z = fmaf(acc.z, rl, b4.z);
  res.w = fmaf(acc.w, rl, b4.w);
  res.x = res.x > 0.f ? res.x : expm1f(res.x);   // ELU
  res.y = res.y > 0.f ? res.y : expm1f(res.y);
  res.z = res.z > 0.f ? res.z : expm1f(res.z);
  res.w = res.w > 0.f ? res.w : expm1f(res.w);
  *(float4*)(hout + (v << 7) + c4) = res;
}

// ---------------- layer 2 fused attention, float4 channels ----------------
// 256 threads = 16 nodes x 16 lanes; 1 head -> 4-stage butterfly over 16 lanes.
__global__ __launch_bounds__(256) void attn2_kernel(
    const float* __restrict__ xl, const float* __restrict__ xr,
    const float* __restrict__ att, const float* __restrict__ bias,
    const int* __restrict__ indptr, const int* __restrict__ csr,
    float* __restrict__ out, int N) {
  const int lane = threadIdx.x & 15;
  const int v = blockIdx.x * 16 + (threadIdx.x >> 4);
  if (v >= N) return;
  const int c4 = lane << 2;
  const float* xlp = xl + c4;                  // + s*64 per edge
  const float4 xr4 = *(const float4*)(xr + (v << 6) + c4);
  const float4 a4  = *(const float4*)(att + c4);
  const int beg = indptr[v];
  const int end = indptr[v + 1];
  float l = 0.f;
  float4 acc = {0.f, 0.f, 0.f, 0.f};
  int e = beg;
  for (; e + 4 <= end; e += 4) {
    const int s0 = csr[e + 0];
    const int s1 = csr[e + 1];
    const int s2 = csr[e + 2];
    const int s3 = csr[e + 3];
    const float4 x0 = *(const float4*)(xlp + (s0 << 6));
    const float4 x1 = *(const float4*)(xlp + (s1 << 6));
    const float4 x2 = *(const float4*)(xlp + (s2 << 6));
    const float4 x3 = *(const float4*)(xlp + (s3 << 6));
    float t0 = lrelu(x0.x + xr4.x) * a4.x + lrelu(x0.y + xr4.y) * a4.y
             + lrelu(x0.z + xr4.z) * a4.z + lrelu(x0.w + xr4.w) * a4.w;
    float t1 = lrelu(x1.x + xr4.x) * a4.x + lrelu(x1.y + xr4.y) * a4.y
             + lrelu(x1.z + xr4.z) * a4.z + lrelu(x1.w + xr4.w) * a4.w;
    float t2 = lrelu(x2.x + xr4.x) * a4.x + lrelu(x2.y + xr4.y) * a4.y
             + lrelu(x2.z + xr4.z) * a4.z + lrelu(x2.w + xr4.w) * a4.w;
    float t3 = lrelu(x3.x + xr4.x) * a4.x + lrelu(x3.y + xr4.y) * a4.y
             + lrelu(x3.z + xr4.z) * a4.z + lrelu(x3.w + xr4.w) * a4.w;
    t0 += __shfl_xor(t0, 1);  t1 += __shfl_xor(t1, 1);
    t2 += __shfl_xor(t2, 1);  t3 += __shfl_xor(t3, 1);
    t0 += __shfl_xor(t0, 2);  t1 += __shfl_xor(t1, 2);
    t2 += __shfl_xor(t2, 2);  t3 += __shfl_xor(t3, 2);
    t0 += __shfl_xor(t0, 4);  t1 += __shfl_xor(t1, 4);
    t2 += __shfl_xor(t2, 4);  t3 += __shfl_xor(t3, 4);
    t0 += __shfl_xor(t0, 8);  t1 += __shfl_xor(t1, 8);
    t2 += __shfl_xor(t2, 8);  t3 += __shfl_xor(t3, 8);
    const float p0 = __expf(t0);
    const float p1 = __expf(t1);
    const float p2 = __expf(t2);
    const float p3 = __expf(t3);
    l += (p0 + p1) + (p2 + p3);
    acc.x = fmaf(p0, x0.x, acc.x); acc.y = fmaf(p0, x0.y, acc.y);
    acc.z = fmaf(p0, x0.z, acc.z); acc.w = fmaf(p0, x0.w, acc.w);
    acc.x = fmaf(p1, x1.x, acc.x); acc.y = fmaf(p1, x1.y, acc.y);
    acc.z = fmaf(p1, x1.z, acc.z); acc.w = fmaf(p1, x1.w, acc.w);
    acc.x = fmaf(p2, x2.x, acc.x); acc.y = fmaf(p2, x2.y, acc.y);
    acc.z = fmaf(p2, x2.z, acc.z); acc.w = fmaf(p2, x2.w, acc.w);
    acc.x = fmaf(p3, x3.x, acc.x); acc.y = fmaf(p3, x3.y, acc.y);
    acc.z = fmaf(p3, x3.z, acc.z); acc.w = fmaf(p3, x3.w, acc.w);
  }
  for (; e < end; ++e) {
    const int s = csr[e];
    const float4 xv = *(const float4*)(xlp + (s << 6));
    float tt = lrelu(xv.x + xr4.x) * a4.x + lrelu(xv.y + xr4.y) * a4.y
             + lrelu(xv.z + xr4.z) * a4.z + lrelu(xv.w + xr4.w) * a4.w;
    tt += __shfl_xor(tt, 1);
    tt += __shfl_xor(tt, 2);
    tt += __shfl_xor(tt, 4);
    tt += __shfl_xor(tt, 8);
    const float p = __expf(tt);
    l += p;
    acc.x = fmaf(p, xv.x, acc.x); acc.y = fmaf(p, xv.y, acc.y);
    acc.z = fmaf(p, xv.z, acc.z); acc.w = fmaf(p, xv.w, acc.w);
  }
  const float rl = 1.f / l;
  const float4 b4 = *(const float4*)(bias + c4);
  float4 res;
  res.x = fmaf(acc.x, rl, b4.x);
  res.y = fmaf(acc.y, rl, b4.y);
  res.z = fmaf(acc.z, rl, b4.z);
  res.w = fmaf(acc.w, rl, b4.w);
  *(float4*)(out + (v << 6) + c4) = res;
}

extern "C" void kernel_launch(void* const* d_in, const int* in_sizes, int n_in,
                              void* d_out, int out_size, void* d_ws, size_t ws_size,
                              hipStream_t stream) {
  const float* x     = (const float*)d_in[0];
  const int*   ei    = (const int*)d_in[1];
  const float* Wl1   = (const float*)d_in[2];
  const float* bl1   = (const float*)d_in[3];
  const float* Wr1   = (const float*)d_in[4];
  const float* br1   = (const float*)d_in[5];
  const float* att1  = (const float*)d_in[6];
  const float* bias1 = (const float*)d_in[7];
  const float* Wl2   = (const float*)d_in[8];
  const float* bl2   = (const float*)d_in[9];
  const float* Wr2   = (const float*)d_in[10];
  const float* br2   = (const float*)d_in[11];
  const float* att2  = (const float*)d_in[12];
  const float* bias2 = (const float*)d_in[13];

  const int N  = in_sizes[0] / FIN;   // 100000
  const int E  = in_sizes[1] / 2;     // 1600000
  const int ET = E + N;

  float* xl1  = (float*)d_ws;                  // N*128
  float* xr1  = xl1 + (size_t)N * F1;          // N*128
  float* hbuf = xr1 + (size_t)N * F1;          // N*128
  int* indptr = (int*)(hbuf + (size_t)N * F1); // N+1
  int* cursor = indptr + (N + 1);              // N (doubles as cnt)
  int* csr    = cursor + N;                    // ET
  int* bsum   = csr + ET;                      // (N+1023)/1024
  float* xl2  = xl1;                           // reuse layer1 region
  float* xr2  = xl1 + (size_t)N * C2;
  float* out  = (float*)d_out;

  const int tb = 256;
  const int eblocks = (ET + tb - 1) / tb;
  const int NB = (N + 1023) / 1024;            // <=1024 supported

  hipMemsetAsync(cursor, 0, (size_t)N * sizeof(int), stream);
  count_deg_kernel<<<eblocks, tb, 0, stream>>>(ei, cursor, E, N);
  scan_partial_kernel<<<NB, 256, 0, stream>>>(cursor, indptr, bsum, N);
  scan_bsum_kernel<<<1, 1024, 0, stream>>>(bsum, indptr, NB, N);
  scan_add_kernel<<<NB, 256, 0, stream>>>(indptr, cursor, bsum, N);
  fill_csr_kernel<<<eblocks, tb, 0, stream>>>(ei, cursor, csr, E, N);

  dim3 g1((N + 63) / 64, F1 / 64, 2);
  gemm_bias2_kernel<<<g1, 256, 0, stream>>>(x, Wl1, bl1, xl1, Wr1, br1, xr1, N, F1);

  attn1_kernel<<<(N + 7) / 8, 256, 0, stream>>>(xl1, xr1, att1, bias1, indptr, csr, hbuf, N);

  dim3 g2((N + 63) / 64, C2 / 64, 2);
  gemm_bias2_kernel<<<g2, 256, 0, stream>>>(hbuf, Wl2, bl2, xl2, Wr2, br2, xr2, N, C2);

  attn2_kernel<<<(N + 15) / 16, 256, 0, stream>>>(xl2, xr2, att2, bias2, indptr, csr, out, N);
}

// Round 5
// 510.346 us; speedup vs baseline: 2.0775x; 1.2567x over previous
//
#include <hip/hip_runtime.h>
#include <math.h>

#define FIN 128   // input features (layer1 K, layer2 K)
#define F1  128   // H1*C1 = layer1 output width
#define C2  64    // layer2 output width
#define NEG 0.2f  // leaky_relu negative slope

#define BKT_SHIFT 8
#define BKT_SIZE  256     // nodes per bucket
#define SCAT_CHUNK 8192   // edges per block in hist/scatter
#define IMGCAP 8192       // LDS csr-image capacity (ints)

__device__ __forceinline__ float lrelu(float z) { return fmaxf(z, NEG * z); }

// ================= bucketed CSR build (dst-grouped, self-loops appended) =================
// Edge item g in [0,ET): g<E -> (ei[g], ei[E+g]); else self-loop (g-E, g-E).
// Packed edge: (src << 8) | (dst & 255). Requires N <= 2^24 and NBKT <= 512.

__global__ __launch_bounds__(256) void bucket_hist_kernel(
    const int* __restrict__ ei, int* __restrict__ bcnt, int E, int ET, int NBKT) {
  __shared__ int sh[512];
  const int t = threadIdx.x;
  for (int b = t; b < NBKT; b += 256) sh[b] = 0;
  __syncthreads();
  const int g0 = blockIdx.x * SCAT_CHUNK + t;
#pragma unroll
  for (int i = 0; i < 32; ++i) {
    const int g = g0 + i * 256;
    if (g < ET) {
      const int dst = (g < E) ? ei[E + g] : (g - E);
      atomicAdd(&sh[dst >> BKT_SHIFT], 1);
    }
  }
  __syncthreads();
  for (int b = t; b < NBKT; b += 256)
    if (sh[b]) atomicAdd(&bcnt[b], sh[b]);
}

__global__ __launch_bounds__(512) void bucket_scan_kernel(
    const int* __restrict__ bcnt, int* __restrict__ bbase, int* __restrict__ bcur,
    int* __restrict__ indptr, int NBKT, int N, int ET) {
  __shared__ int sh[512];
  const int t = threadIdx.x;
  const int v = (t < NBKT) ? bcnt[t] : 0;
  sh[t] = v;
  __syncthreads();
  for (int off = 1; off < 512; off <<= 1) {
    int val = (t >= off) ? sh[t - off] : 0;
    __syncthreads();
    sh[t] += val;
    __syncthreads();
  }
  const int excl = sh[t] - v;
  if (t < NBKT) { bbase[t] = excl; bcur[t] = excl; }
  if (t == NBKT - 1) bbase[NBKT] = excl + v;   // == ET
  if (t == 0) indptr[N] = ET;
}

__global__ __launch_bounds__(256) void bucket_scatter_kernel(
    const int* __restrict__ ei, int* __restrict__ bcur, int* __restrict__ tmp,
    int E, int ET, int NBKT) {
  __shared__ int sh_hist[512];
  __shared__ int sh_base[512];
  const int t = threadIdx.x;
  for (int b = t; b < NBKT; b += 256) sh_hist[b] = 0;
  __syncthreads();
  const int g0 = blockIdx.x * SCAT_CHUNK + t;
  int bk[32], pk[32];
#pragma unroll
  for (int i = 0; i < 32; ++i) {
    const int g = g0 + i * 256;
    int b = -1, p = 0;
    if (g < ET) {
      const int src = (g < E) ? ei[g] : (g - E);
      const int dst = (g < E) ? ei[E + g] : (g - E);
      b = dst >> BKT_SHIFT;
      p = (src << BKT_SHIFT) | (dst & (BKT_SIZE - 1));
      atomicAdd(&sh_hist[b], 1);
    }
    bk[i] = b; pk[i] = p;
  }
  __syncthreads();
  for (int b = t; b < NBKT; b += 256) {
    const int c = sh_hist[b];
    sh_base[b] = c ? atomicAdd(&bcur[b], c) : 0;
    sh_hist[b] = 0;   // reuse as in-block cursor
  }
  __syncthreads();
#pragma unroll
  for (int i = 0; i < 32; ++i) {
    if (bk[i] >= 0) {
      const int off = atomicAdd(&sh_hist[bk[i]], 1);
      tmp[sh_base[bk[i]] + off] = pk[i];
    }
  }
}

// One block per bucket: per-node counts -> LDS scan -> indptr write,
// scatter into LDS image, coalesced copy to csr.
__global__ __launch_bounds__(256) void build_csr_kernel(
    const int* __restrict__ tmp, const int* __restrict__ bbase,
    int* __restrict__ indptr, int* __restrict__ csr, int N) {
  __shared__ int cnt[256];
  __shared__ int cur[256];
  __shared__ int img[IMGCAP];
  const int b = blockIdx.x;
  const int t = threadIdx.x;
  const int base = bbase[b];
  const int cntb = bbase[b + 1] - base;
  cnt[t] = 0;
  __syncthreads();
  for (int i = t; i < cntb; i += 256)
    atomicAdd(&cnt[tmp[base + i] & (BKT_SIZE - 1)], 1);
  __syncthreads();
  const int v = cnt[t];
  cur[t] = v;
  __syncthreads();
  for (int off = 1; off < 256; off <<= 1) {
    int val = (t >= off) ? cur[t - off] : 0;
    __syncthreads();
    cur[t] += val;
    __syncthreads();
  }
  const int excl = cur[t] - v;     // exclusive prefix within bucket
  const int node = (b << BKT_SHIFT) + t;
  if (node < N) indptr[node] = base + excl;
  __syncthreads();
  cur[t] = excl;                   // local cursor
  __syncthreads();
  if (cntb <= IMGCAP) {
    for (int i = t; i < cntb; i += 256) {
      const int p = tmp[base + i];
      const int pos = atomicAdd(&cur[p & (BKT_SIZE - 1)], 1);
      img[pos] = p >> BKT_SHIFT;
    }
    __syncthreads();
    for (int i = t; i < cntb; i += 256) csr[base + i] = img[i];
  } else {  // fallback for pathological buckets: scattered but correct
    for (int i = t; i < cntb; i += 256) {
      const int p = tmp[base + i];
      const int pos = atomicAdd(&cur[p & (BKT_SIZE - 1)], 1);
      csr[base + pos] = p >> BKT_SHIFT;
    }
  }
}

// ---------------- fp32 GEMM: O{0,1}[M,Ncols] = A[M,128] @ W{0,1}[128,Ncols] + b{0,1} ----------------
__global__ __launch_bounds__(256) void gemm_bias2_kernel(
    const float* __restrict__ A,
    const float* __restrict__ W0, const float* __restrict__ b0, float* __restrict__ O0,
    const float* __restrict__ W1, const float* __restrict__ b1, float* __restrict__ O1,
    int M, int Ncols) {
  const float* W    = blockIdx.z ? W1 : W0;
  const float* bias = blockIdx.z ? b1 : b0;
  float* out        = blockIdx.z ? O1 : O0;
  __shared__ float As[16][68];
  __shared__ float Ws[16][68];
  const int tid = threadIdx.x;
  const int r0 = blockIdx.x * 64;
  const int c0 = blockIdx.y * 64;
  const int tm = tid >> 4;
  const int tc = tid & 15;
  const int la_row = tid >> 2;
  const int la_k4  = (tid & 3) << 2;
  const int lw_k   = tid >> 4;
  const int lw_c4  = (tid & 15) << 2;
  const int arow = min(r0 + la_row, M - 1);
  float acc[4][4] = {{0.f, 0.f, 0.f, 0.f}, {0.f, 0.f, 0.f, 0.f},
                     {0.f, 0.f, 0.f, 0.f}, {0.f, 0.f, 0.f, 0.f}};
  for (int k0 = 0; k0 < FIN; k0 += 16) {
    const float4 av = *(const float4*)(A + (size_t)arow * FIN + k0 + la_k4);
    const float4 wv = *(const float4*)(W + (size_t)(k0 + lw_k) * Ncols + c0 + lw_c4);
    __syncthreads();
    As[la_k4 + 0][la_row] = av.x;
    As[la_k4 + 1][la_row] = av.y;
    As[la_k4 + 2][la_row] = av.z;
    As[la_k4 + 3][la_row] = av.w;
    *(float4*)(&Ws[lw_k][lw_c4]) = wv;
    __syncthreads();
#pragma unroll
    for (int kk = 0; kk < 16; ++kk) {
      const float4 a4 = *(const float4*)(&As[kk][tm << 2]);
      const float4 w4 = *(const float4*)(&Ws[kk][tc << 2]);
      acc[0][0] = fmaf(a4.x, w4.x, acc[0][0]);
      acc[0][1] = fmaf(a4.x, w4.y, acc[0][1]);
      acc[0][2] = fmaf(a4.x, w4.z, acc[0][2]);
      acc[0][3] = fmaf(a4.x, w4.w, acc[0][3]);
      acc[1][0] = fmaf(a4.y, w4.x, acc[1][0]);
      acc[1][1] = fmaf(a4.y, w4.y, acc[1][1]);
      acc[1][2] = fmaf(a4.y, w4.z, acc[1][2]);
      acc[1][3] = fmaf(a4.y, w4.w, acc[1][3]);
      acc[2][0] = fmaf(a4.z, w4.x, acc[2][0]);
      acc[2][1] = fmaf(a4.z, w4.y, acc[2][1]);
      acc[2][2] = fmaf(a4.z, w4.z, acc[2][2]);
      acc[2][3] = fmaf(a4.z, w4.w, acc[2][3]);
      acc[3][0] = fmaf(a4.w, w4.x, acc[3][0]);
      acc[3][1] = fmaf(a4.w, w4.y, acc[3][1]);
      acc[3][2] = fmaf(a4.w, w4.z, acc[3][2]);
      acc[3][3] = fmaf(a4.w, w4.w, acc[3][3]);
    }
  }
  const float4 b4 = *(const float4*)(bias + c0 + (tc << 2));
#pragma unroll
  for (int i = 0; i < 4; ++i) {
    int r = r0 + (tm << 2) + i;
    if (r < M) {
      float4 o;
      o.x = acc[i][0] + b4.x;
      o.y = acc[i][1] + b4.y;
      o.z = acc[i][2] + b4.z;
      o.w = acc[i][3] + b4.w;
      *(float4*)(out + (size_t)r * Ncols + c0 + (tc << 2)) = o;
    }
  }
}

// ---------------- layer 1 fused attention, float4 channels ----------------
__global__ __launch_bounds__(256) void attn1_kernel(
    const float* __restrict__ xl, const float* __restrict__ xr,
    const float* __restrict__ att, const float* __restrict__ bias,
    const int* __restrict__ indptr, const int* __restrict__ csr,
    float* __restrict__ hout, int N) {
  const int lane = threadIdx.x & 31;
  const int v = blockIdx.x * 8 + (threadIdx.x >> 5);
  if (v >= N) return;
  const int c4 = lane << 2;
  const float* xlp = xl + c4;
  const float4 xr4 = *(const float4*)(xr + (v << 7) + c4);
  const float4 a4  = *(const float4*)(att + c4);
  const int beg = indptr[v];
  const int end = indptr[v + 1];
  float l = 0.f;
  float4 acc = {0.f, 0.f, 0.f, 0.f};
  int e = beg;
  for (; e + 4 <= end; e += 4) {
    const int s0 = csr[e + 0];
    const int s1 = csr[e + 1];
    const int s2 = csr[e + 2];
    const int s3 = csr[e + 3];
    const float4 x0 = *(const float4*)(xlp + (s0 << 7));
    const float4 x1 = *(const float4*)(xlp + (s1 << 7));
    const float4 x2 = *(const float4*)(xlp + (s2 << 7));
    const float4 x3 = *(const float4*)(xlp + (s3 << 7));
    float t0 = lrelu(x0.x + xr4.x) * a4.x + lrelu(x0.y + xr4.y) * a4.y
             + lrelu(x0.z + xr4.z) * a4.z + lrelu(x0.w + xr4.w) * a4.w;
    float t1 = lrelu(x1.x + xr4.x) * a4.x + lrelu(x1.y + xr4.y) * a4.y
             + lrelu(x1.z + xr4.z) * a4.z + lrelu(x1.w + xr4.w) * a4.w;
    float t2 = lrelu(x2.x + xr4.x) * a4.x + lrelu(x2.y + xr4.y) * a4.y
             + lrelu(x2.z + xr4.z) * a4.z + lrelu(x2.w + xr4.w) * a4.w;
    float t3 = lrelu(x3.x + xr4.x) * a4.x + lrelu(x3.y + xr4.y) * a4.y
             + lrelu(x3.z + xr4.z) * a4.z + lrelu(x3.w + xr4.w) * a4.w;
    t0 += __shfl_xor(t0, 1);  t1 += __shfl_xor(t1, 1);
    t2 += __shfl_xor(t2, 1);  t3 += __shfl_xor(t3, 1);
    t0 += __shfl_xor(t0, 2);  t1 += __shfl_xor(t1, 2);
    t2 += __shfl_xor(t2, 2);  t3 += __shfl_xor(t3, 2);
    const float p0 = __expf(t0);
    const float p1 = __expf(t1);
    const float p2 = __expf(t2);
    const float p3 = __expf(t3);
    l += (p0 + p1) + (p2 + p3);
    acc.x = fmaf(p0, x0.x, acc.x); acc.y = fmaf(p0, x0.y, acc.y);
    acc.z = fmaf(p0, x0.z, acc.z); acc.w = fmaf(p0, x0.w, acc.w);
    acc.x = fmaf(p1, x1.x, acc.x); acc.y = fmaf(p1, x1.y, acc.y);
    acc.z = fmaf(p1, x1.z, acc.z); acc.w = fmaf(p1, x1.w, acc.w);
    acc.x = fmaf(p2, x2.x, acc.x); acc.y = fmaf(p2, x2.y, acc.y);
    acc.z = fmaf(p2, x2.z, acc.z); acc.w = fmaf(p2, x2.w, acc.w);
    acc.x = fmaf(p3, x3.x, acc.x); acc.y = fmaf(p3, x3.y, acc.y);
    acc.z = fmaf(p3, x3.z, acc.z); acc.w = fmaf(p3, x3.w, acc.w);
  }
  for (; e < end; ++e) {
    const int s = csr[e];
    const float4 xv = *(const float4*)(xlp + (s << 7));
    float tt = lrelu(xv.x + xr4.x) * a4.x + lrelu(xv.y + xr4.y) * a4.y
             + lrelu(xv.z + xr4.z) * a4.z + lrelu(xv.w + xr4.w) * a4.w;
    tt += __shfl_xor(tt, 1);
    tt += __shfl_xor(tt, 2);
    const float p = __expf(tt);
    l += p;
    acc.x = fmaf(p, xv.x, acc.x); acc.y = fmaf(p, xv.y, acc.y);
    acc.z = fmaf(p, xv.z, acc.z); acc.w = fmaf(p, xv.w, acc.w);
  }
  const float rl = 1.f / l;
  const float4 b4 = *(const float4*)(bias + c4);
  float4 res;
  res.x = fmaf(acc.x, rl, b4.x);
  res.y = fmaf(acc.y, rl, b4.y);
  res.z = fmaf(acc.z, rl, b4.z);
  res.w = fmaf(acc.w, rl, b4.w);
  res.x = res.x > 0.f ? res.x : expm1f(res.x);   // ELU
  res.y = res.y > 0.f ? res.y : expm1f(res.y);
  res.z = res.z > 0.f ? res.z : expm1f(res.z);
  res.w = res.w > 0.f ? res.w : expm1f(res.w);
  *(float4*)(hout + (v << 7) + c4) = res;
}

// ---------------- layer 2 fused attention, float4 channels ----------------
__global__ __launch_bounds__(256) void attn2_kernel(
    const float* __restrict__ xl, const float* __restrict__ xr,
    const float* __restrict__ att, const float* __restrict__ bias,
    const int* __restrict__ indptr, const int* __restrict__ csr,
    float* __restrict__ out, int N) {
  const int lane = threadIdx.x & 15;
  const int v = blockIdx.x * 16 + (threadIdx.x >> 4);
  if (v >= N) return;
  const int c4 = lane << 2;
  const float* xlp = xl + c4;
  const float4 xr4 = *(const float4*)(xr + (v << 6) + c4);
  const float4 a4  = *(const float4*)(att + c4);
  const int beg = indptr[v];
  const int end = indptr[v + 1];
  float l = 0.f;
  float4 acc = {0.f, 0.f, 0.f, 0.f};
  int e = beg;
  for (; e + 4 <= end; e += 4) {
    const int s0 = csr[e + 0];
    const int s1 = csr[e + 1];
    const int s2 = csr[e + 2];
    const int s3 = csr[e + 3];
    const float4 x0 = *(const float4*)(xlp + (s0 << 6));
    const float4 x1 = *(const float4*)(xlp + (s1 << 6));
    const float4 x2 = *(const float4*)(xlp + (s2 << 6));
    const float4 x3 = *(const float4*)(xlp + (s3 << 6));
    float t0 = lrelu(x0.x + xr4.x) * a4.x + lrelu(x0.y + xr4.y) * a4.y
             + lrelu(x0.z + xr4.z) * a4.z + lrelu(x0.w + xr4.w) * a4.w;
    float t1 = lrelu(x1.x + xr4.x) * a4.x + lrelu(x1.y + xr4.y) * a4.y
             + lrelu(x1.z + xr4.z) * a4.z + lrelu(x1.w + xr4.w) * a4.w;
    float t2 = lrelu(x2.x + xr4.x) * a4.x + lrelu(x2.y + xr4.y) * a4.y
             + lrelu(x2.z + xr4.z) * a4.z + lrelu(x2.w + xr4.w) * a4.w;
    float t3 = lrelu(x3.x + xr4.x) * a4.x + lrelu(x3.y + xr4.y) * a4.y
             + lrelu(x3.z + xr4.z) * a4.z + lrelu(x3.w + xr4.w) * a4.w;
    t0 += __shfl_xor(t0, 1);  t1 += __shfl_xor(t1, 1);
    t2 += __shfl_xor(t2, 1);  t3 += __shfl_xor(t3, 1);
    t0 += __shfl_xor(t0, 2);  t1 += __shfl_xor(t1, 2);
    t2 += __shfl_xor(t2, 2);  t3 += __shfl_xor(t3, 2);
    t0 += __shfl_xor(t0, 4);  t1 += __shfl_xor(t1, 4);
    t2 += __shfl_xor(t2, 4);  t3 += __shfl_xor(t3, 4);
    t0 += __shfl_xor(t0, 8);  t1 += __shfl_xor(t1, 8);
    t2 += __shfl_xor(t2, 8);  t3 += __shfl_xor(t3, 8);
    const float p0 = __expf(t0);
    const float p1 = __expf(t1);
    const float p2 = __expf(t2);
    const float p3 = __expf(t3);
    l += (p0 + p1) + (p2 + p3);
    acc.x = fmaf(p0, x0.x, acc.x); acc.y = fmaf(p0, x0.y, acc.y);
    acc.z = fmaf(p0, x0.z, acc.z); acc.w = fmaf(p0, x0.w, acc.w);
    acc.x = fmaf(p1, x1.x, acc.x); acc.y = fmaf(p1, x1.y, acc.y);
    acc.z = fmaf(p1, x1.z, acc.z); acc.w = fmaf(p1, x1.w, acc.w);
    acc.x = fmaf(p2, x2.x, acc.x); acc.y = fmaf(p2, x2.y, acc.y);
    acc.z = fmaf(p2, x2.z, acc.z); acc.w = fmaf(p2, x2.w, acc.w);
    acc.x = fmaf(p3, x3.x, acc.x); acc.y = fmaf(p3, x3.y, acc.y);
    acc.z = fmaf(p3, x3.z, acc.z); acc.w = fmaf(p3, x3.w, acc.w);
  }
  for (; e < end; ++e) {
    const int s = csr[e];
    const float4 xv = *(const float4*)(xlp + (s << 6));
    float tt = lrelu(xv.x + xr4.x) * a4.x + lrelu(xv.y + xr4.y) * a4.y
             + lrelu(xv.z + xr4.z) * a4.z + lrelu(xv.w + xr4.w) * a4.w;
    tt += __shfl_xor(tt, 1);
    tt += __shfl_xor(tt, 2);
    tt += __shfl_xor(tt, 4);
    tt += __shfl_xor(tt, 8);
    const float p = __expf(tt);
    l += p;
    acc.x = fmaf(p, xv.x, acc.x); acc.y = fmaf(p, xv.y, acc.y);
    acc.z = fmaf(p, xv.z, acc.z); acc.w = fmaf(p, xv.w, acc.w);
  }
  const float rl = 1.f / l;
  const float4 b4 = *(const float4*)(bias + c4);
  float4 res;
  res.x = fmaf(acc.x, rl, b4.x);
  res.y = fmaf(acc.y, rl, b4.y);
  res.z = fmaf(acc.z, rl, b4.z);
  res.w = fmaf(acc.w, rl, b4.w);
  *(float4*)(out + (v << 6) + c4) = res;
}

extern "C" void kernel_launch(void* const* d_in, const int* in_sizes, int n_in,
                              void* d_out, int out_size, void* d_ws, size_t ws_size,
                              hipStream_t stream) {
  const float* x     = (const float*)d_in[0];
  const int*   ei    = (const int*)d_in[1];
  const float* Wl1   = (const float*)d_in[2];
  const float* bl1   = (const float*)d_in[3];
  const float* Wr1   = (const float*)d_in[4];
  const float* br1   = (const float*)d_in[5];
  const float* att1  = (const float*)d_in[6];
  const float* bias1 = (const float*)d_in[7];
  const float* Wl2   = (const float*)d_in[8];
  const float* bl2   = (const float*)d_in[9];
  const float* Wr2   = (const float*)d_in[10];
  const float* br2   = (const float*)d_in[11];
  const float* att2  = (const float*)d_in[12];
  const float* bias2 = (const float*)d_in[13];

  const int N  = in_sizes[0] / FIN;   // 100000
  const int E  = in_sizes[1] / 2;     // 1600000
  const int ET = E + N;
  const int NBKT = (N + BKT_SIZE - 1) >> BKT_SHIFT;   // 391 (<=512 required)

  float* xl1  = (float*)d_ws;                  // N*128
  float* xr1  = xl1 + (size_t)N * F1;          // N*128
  float* hbuf = xr1 + (size_t)N * F1;          // N*128
  int* indptr = (int*)(hbuf + (size_t)N * F1); // N+1
  int* csr    = indptr + (N + 1);              // ET
  int* bcnt   = csr + ET;                      // 512
  int* bbase  = bcnt + 512;                    // 513
  int* bcur   = bbase + 513;                   // 512
  int* tmp    = (int*)hbuf;                    // alias: dead before attn1 writes hbuf
  float* xl2  = xl1;                           // reuse layer1 region
  float* xr2  = xl1 + (size_t)N * C2;
  float* out  = (float*)d_out;

  const int sblocks = (ET + SCAT_CHUNK - 1) / SCAT_CHUNK;

  hipMemsetAsync(bcnt, 0, 512 * sizeof(int), stream);
  bucket_hist_kernel<<<sblocks, 256, 0, stream>>>(ei, bcnt, E, ET, NBKT);
  bucket_scan_kernel<<<1, 512, 0, stream>>>(bcnt, bbase, bcur, indptr, NBKT, N, ET);
  bucket_scatter_kernel<<<sblocks, 256, 0, stream>>>(ei, bcur, tmp, E, ET, NBKT);
  build_csr_kernel<<<NBKT, 256, 0, stream>>>(tmp, bbase, indptr, csr, N);

  dim3 g1((N + 63) / 64, F1 / 64, 2);
  gemm_bias2_kernel<<<g1, 256, 0, stream>>>(x, Wl1, bl1, xl1, Wr1, br1, xr1, N, F1);

  attn1_kernel<<<(N + 7) / 8, 256, 0, stream>>>(xl1, xr1, att1, bias1, indptr, csr, hbuf, N);

  dim3 g2((N + 63) / 64, C2 / 64, 2);
  gemm_bias2_kernel<<<g2, 256, 0, stream>>>(hbuf, Wl2, bl2, xl2, Wr2, br2, xr2, N, C2);

  attn2_kernel<<<(N + 15) / 16, 256, 0, stream>>>(xl2, xr2, att2, bias2, indptr, csr, out, N);
}

// Round 6
// 437.839 us; speedup vs baseline: 2.4215x; 1.1656x over previous
//
#include <hip/hip_runtime.h>
#include <math.h>

#define FIN 128   // input features (layer1 K, layer2 K)
#define F1  128   // H1*C1 = layer1 output width
#define C2  64    // layer2 output width
#define NEG 0.2f  // leaky_relu negative slope

#define BKT_SHIFT 8
#define BKT_SIZE  256     // nodes per bucket
#define SCAT_CHUNK 8192   // edges per block in hist/scatter
#define IMGCAP 8192       // LDS csr-image capacity (ints)

typedef _Float16 half4 __attribute__((ext_vector_type(4)));

__device__ __forceinline__ float lrelu(float z) { return fmaxf(z, NEG * z); }

// ================= bucketed CSR build (dst-grouped, self-loops appended) =================
__global__ __launch_bounds__(256) void bucket_hist_kernel(
    const int* __restrict__ ei, int* __restrict__ bcnt, int E, int ET, int NBKT) {
  __shared__ int sh[512];
  const int t = threadIdx.x;
  for (int b = t; b < NBKT; b += 256) sh[b] = 0;
  __syncthreads();
  const int g0 = blockIdx.x * SCAT_CHUNK + t;
#pragma unroll
  for (int i = 0; i < 32; ++i) {
    const int g = g0 + i * 256;
    if (g < ET) {
      const int dst = (g < E) ? ei[E + g] : (g - E);
      atomicAdd(&sh[dst >> BKT_SHIFT], 1);
    }
  }
  __syncthreads();
  for (int b = t; b < NBKT; b += 256)
    if (sh[b]) atomicAdd(&bcnt[b], sh[b]);
}

__global__ __launch_bounds__(512) void bucket_scan_kernel(
    const int* __restrict__ bcnt, int* __restrict__ bbase, int* __restrict__ bcur,
    int* __restrict__ indptr, int NBKT, int N, int ET) {
  __shared__ int sh[512];
  const int t = threadIdx.x;
  const int v = (t < NBKT) ? bcnt[t] : 0;
  sh[t] = v;
  __syncthreads();
  for (int off = 1; off < 512; off <<= 1) {
    int val = (t >= off) ? sh[t - off] : 0;
    __syncthreads();
    sh[t] += val;
    __syncthreads();
  }
  const int excl = sh[t] - v;
  if (t < NBKT) { bbase[t] = excl; bcur[t] = excl; }
  if (t == NBKT - 1) bbase[NBKT] = excl + v;   // == ET
  if (t == 0) indptr[N] = ET;
}

__global__ __launch_bounds__(256) void bucket_scatter_kernel(
    const int* __restrict__ ei, int* __restrict__ bcur, int* __restrict__ tmp,
    int E, int ET, int NBKT) {
  __shared__ int sh_hist[512];
  __shared__ int sh_base[512];
  const int t = threadIdx.x;
  for (int b = t; b < NBKT; b += 256) sh_hist[b] = 0;
  __syncthreads();
  const int g0 = blockIdx.x * SCAT_CHUNK + t;
  int bk[32], pk[32];
#pragma unroll
  for (int i = 0; i < 32; ++i) {
    const int g = g0 + i * 256;
    int b = -1, p = 0;
    if (g < ET) {
      const int src = (g < E) ? ei[g] : (g - E);
      const int dst = (g < E) ? ei[E + g] : (g - E);
      b = dst >> BKT_SHIFT;
      p = (src << BKT_SHIFT) | (dst & (BKT_SIZE - 1));
      atomicAdd(&sh_hist[b], 1);
    }
    bk[i] = b; pk[i] = p;
  }
  __syncthreads();
  for (int b = t; b < NBKT; b += 256) {
    const int c = sh_hist[b];
    sh_base[b] = c ? atomicAdd(&bcur[b], c) : 0;
    sh_hist[b] = 0;   // reuse as in-block cursor
  }
  __syncthreads();
#pragma unroll
  for (int i = 0; i < 32; ++i) {
    if (bk[i] >= 0) {
      const int off = atomicAdd(&sh_hist[bk[i]], 1);
      tmp[sh_base[bk[i]] + off] = pk[i];
    }
  }
}

__global__ __launch_bounds__(256) void build_csr_kernel(
    const int* __restrict__ tmp, const int* __restrict__ bbase,
    int* __restrict__ indptr, int* __restrict__ csr, int N) {
  __shared__ int cnt[256];
  __shared__ int cur[256];
  __shared__ int img[IMGCAP];
  const int b = blockIdx.x;
  const int t = threadIdx.x;
  const int base = bbase[b];
  const int cntb = bbase[b + 1] - base;
  cnt[t] = 0;
  __syncthreads();
  for (int i = t; i < cntb; i += 256)
    atomicAdd(&cnt[tmp[base + i] & (BKT_SIZE - 1)], 1);
  __syncthreads();
  const int v = cnt[t];
  cur[t] = v;
  __syncthreads();
  for (int off = 1; off < 256; off <<= 1) {
    int val = (t >= off) ? cur[t - off] : 0;
    __syncthreads();
    cur[t] += val;
    __syncthreads();
  }
  const int excl = cur[t] - v;
  const int node = (b << BKT_SHIFT) + t;
  if (node < N) indptr[node] = base + excl;
  __syncthreads();
  cur[t] = excl;
  __syncthreads();
  if (cntb <= IMGCAP) {
    for (int i = t; i < cntb; i += 256) {
      const int p = tmp[base + i];
      const int pos = atomicAdd(&cur[p & (BKT_SIZE - 1)], 1);
      img[pos] = p >> BKT_SHIFT;
    }
    __syncthreads();
    for (int i = t; i < cntb; i += 256) csr[base + i] = img[i];
  } else {
    for (int i = t; i < cntb; i += 256) {
      const int p = tmp[base + i];
      const int pos = atomicAdd(&cur[p & (BKT_SIZE - 1)], 1);
      csr[base + pos] = p >> BKT_SHIFT;
    }
  }
}

// ---------------- fp32 GEMM, dual output: z=0 -> fp16 store (xl), z=1 -> fp32 store (xr) ----------------
__global__ __launch_bounds__(256) void gemm_bias2_kernel(
    const float* __restrict__ A,
    const float* __restrict__ W0, const float* __restrict__ b0, _Float16* __restrict__ O0h,
    const float* __restrict__ W1, const float* __restrict__ b1, float* __restrict__ O1,
    int M, int Ncols) {
  const int zsel = blockIdx.z;
  const float* W    = zsel ? W1 : W0;
  const float* bias = zsel ? b1 : b0;
  __shared__ float As[16][68];
  __shared__ float Ws[16][68];
  const int tid = threadIdx.x;
  const int r0 = blockIdx.x * 64;
  const int c0 = blockIdx.y * 64;
  const int tm = tid >> 4;
  const int tc = tid & 15;
  const int la_row = tid >> 2;
  const int la_k4  = (tid & 3) << 2;
  const int lw_k   = tid >> 4;
  const int lw_c4  = (tid & 15) << 2;
  const int arow = min(r0 + la_row, M - 1);
  float acc[4][4] = {{0.f, 0.f, 0.f, 0.f}, {0.f, 0.f, 0.f, 0.f},
                     {0.f, 0.f, 0.f, 0.f}, {0.f, 0.f, 0.f, 0.f}};
  for (int k0 = 0; k0 < FIN; k0 += 16) {
    const float4 av = *(const float4*)(A + (size_t)arow * FIN + k0 + la_k4);
    const float4 wv = *(const float4*)(W + (size_t)(k0 + lw_k) * Ncols + c0 + lw_c4);
    __syncthreads();
    As[la_k4 + 0][la_row] = av.x;
    As[la_k4 + 1][la_row] = av.y;
    As[la_k4 + 2][la_row] = av.z;
    As[la_k4 + 3][la_row] = av.w;
    *(float4*)(&Ws[lw_k][lw_c4]) = wv;
    __syncthreads();
#pragma unroll
    for (int kk = 0; kk < 16; ++kk) {
      const float4 a4 = *(const float4*)(&As[kk][tm << 2]);
      const float4 w4 = *(const float4*)(&Ws[kk][tc << 2]);
      acc[0][0] = fmaf(a4.x, w4.x, acc[0][0]);
      acc[0][1] = fmaf(a4.x, w4.y, acc[0][1]);
      acc[0][2] = fmaf(a4.x, w4.z, acc[0][2]);
      acc[0][3] = fmaf(a4.x, w4.w, acc[0][3]);
      acc[1][0] = fmaf(a4.y, w4.x, acc[1][0]);
      acc[1][1] = fmaf(a4.y, w4.y, acc[1][1]);
      acc[1][2] = fmaf(a4.y, w4.z, acc[1][2]);
      acc[1][3] = fmaf(a4.y, w4.w, acc[1][3]);
      acc[2][0] = fmaf(a4.z, w4.x, acc[2][0]);
      acc[2][1] = fmaf(a4.z, w4.y, acc[2][1]);
      acc[2][2] = fmaf(a4.z, w4.z, acc[2][2]);
      acc[2][3] = fmaf(a4.z, w4.w, acc[2][3]);
      acc[3][0] = fmaf(a4.w, w4.x, acc[3][0]);
      acc[3][1] = fmaf(a4.w, w4.y, acc[3][1]);
      acc[3][2] = fmaf(a4.w, w4.z, acc[3][2]);
      acc[3][3] = fmaf(a4.w, w4.w, acc[3][3]);
    }
  }
  const float4 b4 = *(const float4*)(bias + c0 + (tc << 2));
  if (zsel) {
#pragma unroll
    for (int i = 0; i < 4; ++i) {
      int r = r0 + (tm << 2) + i;
      if (r < M) {
        float4 o;
        o.x = acc[i][0] + b4.x;
        o.y = acc[i][1] + b4.y;
        o.z = acc[i][2] + b4.z;
        o.w = acc[i][3] + b4.w;
        *(float4*)(O1 + (size_t)r * Ncols + c0 + (tc << 2)) = o;
      }
    }
  } else {
#pragma unroll
    for (int i = 0; i < 4; ++i) {
      int r = r0 + (tm << 2) + i;
      if (r < M) {
        half4 o;
        o.x = (_Float16)(acc[i][0] + b4.x);
        o.y = (_Float16)(acc[i][1] + b4.y);
        o.z = (_Float16)(acc[i][2] + b4.z);
        o.w = (_Float16)(acc[i][3] + b4.w);
        *(half4*)(O0h + (size_t)r * Ncols + c0 + (tc << 2)) = o;
      }
    }
  }
}

// ---------------- layer 1 fused attention: fp16 gather, float4 math ----------------
// 256 threads = 8 nodes x 32 lanes; lane owns chans [4*lane .. 4*lane+3].
__global__ __launch_bounds__(256) void attn1_kernel(
    const _Float16* __restrict__ xl, const float* __restrict__ xr,
    const float* __restrict__ att, const float* __restrict__ bias,
    const int* __restrict__ indptr, const int* __restrict__ csr,
    float* __restrict__ hout, int N) {
  const int lane = threadIdx.x & 31;
  const int v = blockIdx.x * 8 + (threadIdx.x >> 5);
  if (v >= N) return;
  const int c4 = lane << 2;
  const _Float16* xlp = xl + c4;
  const float4 xr4 = *(const float4*)(xr + (v << 7) + c4);
  const float4 a4  = *(const float4*)(att + c4);
  const int beg = indptr[v];
  const int end = indptr[v + 1];
  float l = 0.f;
  float4 acc = {0.f, 0.f, 0.f, 0.f};
  int e = beg;
  for (; e + 4 <= end; e += 4) {
    const int s0 = csr[e + 0];
    const int s1 = csr[e + 1];
    const int s2 = csr[e + 2];
    const int s3 = csr[e + 3];
    const half4 h0 = *(const half4*)(xlp + (s0 << 7));
    const half4 h1 = *(const half4*)(xlp + (s1 << 7));
    const half4 h2 = *(const half4*)(xlp + (s2 << 7));
    const half4 h3 = *(const half4*)(xlp + (s3 << 7));
    const float4 x0 = {(float)h0.x, (float)h0.y, (float)h0.z, (float)h0.w};
    const float4 x1 = {(float)h1.x, (float)h1.y, (float)h1.z, (float)h1.w};
    const float4 x2 = {(float)h2.x, (float)h2.y, (float)h2.z, (float)h2.w};
    const float4 x3 = {(float)h3.x, (float)h3.y, (float)h3.z, (float)h3.w};
    float t0 = lrelu(x0.x + xr4.x) * a4.x + lrelu(x0.y + xr4.y) * a4.y
             + lrelu(x0.z + xr4.z) * a4.z + lrelu(x0.w + xr4.w) * a4.w;
    float t1 = lrelu(x1.x + xr4.x) * a4.x + lrelu(x1.y + xr4.y) * a4.y
             + lrelu(x1.z + xr4.z) * a4.z + lrelu(x1.w + xr4.w) * a4.w;
    float t2 = lrelu(x2.x + xr4.x) * a4.x + lrelu(x2.y + xr4.y) * a4.y
             + lrelu(x2.z + xr4.z) * a4.z + lrelu(x2.w + xr4.w) * a4.w;
    float t3 = lrelu(x3.x + xr4.x) * a4.x + lrelu(x3.y + xr4.y) * a4.y
             + lrelu(x3.z + xr4.z) * a4.z + lrelu(x3.w + xr4.w) * a4.w;
    t0 += __shfl_xor(t0, 1);  t1 += __shfl_xor(t1, 1);
    t2 += __shfl_xor(t2, 1);  t3 += __shfl_xor(t3, 1);
    t0 += __shfl_xor(t0, 2);  t1 += __shfl_xor(t1, 2);
    t2 += __shfl_xor(t2, 2);  t3 += __shfl_xor(t3, 2);
    const float p0 = __expf(t0);
    const float p1 = __expf(t1);
    const float p2 = __expf(t2);
    const float p3 = __expf(t3);
    l += (p0 + p1) + (p2 + p3);
    acc.x = fmaf(p0, x0.x, acc.x); acc.y = fmaf(p0, x0.y, acc.y);
    acc.z = fmaf(p0, x0.z, acc.z); acc.w = fmaf(p0, x0.w, acc.w);
    acc.x = fmaf(p1, x1.x, acc.x); acc.y = fmaf(p1, x1.y, acc.y);
    acc.z = fmaf(p1, x1.z, acc.z); acc.w = fmaf(p1, x1.w, acc.w);
    acc.x = fmaf(p2, x2.x, acc.x); acc.y = fmaf(p2, x2.y, acc.y);
    acc.z = fmaf(p2, x2.z, acc.z); acc.w = fmaf(p2, x2.w, acc.w);
    acc.x = fmaf(p3, x3.x, acc.x); acc.y = fmaf(p3, x3.y, acc.y);
    acc.z = fmaf(p3, x3.z, acc.z); acc.w = fmaf(p3, x3.w, acc.w);
  }
  for (; e < end; ++e) {
    const int s = csr[e];
    const half4 hv = *(const half4*)(xlp + (s << 7));
    const float4 xv = {(float)hv.x, (float)hv.y, (float)hv.z, (float)hv.w};
    float tt = lrelu(xv.x + xr4.x) * a4.x + lrelu(xv.y + xr4.y) * a4.y
             + lrelu(xv.z + xr4.z) * a4.z + lrelu(xv.w + xr4.w) * a4.w;
    tt += __shfl_xor(tt, 1);
    tt += __shfl_xor(tt, 2);
    const float p = __expf(tt);
    l += p;
    acc.x = fmaf(p, xv.x, acc.x); acc.y = fmaf(p, xv.y, acc.y);
    acc.z = fmaf(p, xv.z, acc.z); acc.w = fmaf(p, xv.w, acc.w);
  }
  const float rl = 1.f / l;
  const float4 b4 = *(const float4*)(bias + c4);
  float4 res;
  res.x = fmaf(acc.x, rl, b4.x);
  res.y = fmaf(acc.y, rl, b4.y);
  res.z = fmaf(acc.z, rl, b4.z);
  res.w = fmaf(acc.w, rl, b4.w);
  res.x = res.x > 0.f ? res.x : expm1f(res.x);   // ELU
  res.y = res.y > 0.f ? res.y : expm1f(res.y);
  res.z = res.z > 0.f ? res.z : expm1f(res.z);
  res.w = res.w > 0.f ? res.w : expm1f(res.w);
  *(float4*)(hout + (v << 7) + c4) = res;
}

// ---------------- layer 2 fused attention: fp16 gather ----------------
// 256 threads = 16 nodes x 16 lanes.
__global__ __launch_bounds__(256) void attn2_kernel(
    const _Float16* __restrict__ xl, const float* __restrict__ xr,
    const float* __restrict__ att, const float* __restrict__ bias,
    const int* __restrict__ indptr, const int* __restrict__ csr,
    float* __restrict__ out, int N) {
  const int lane = threadIdx.x & 15;
  const int v = blockIdx.x * 16 + (threadIdx.x >> 4);
  if (v >= N) return;
  const int c4 = lane << 2;
  const _Float16* xlp = xl + c4;
  const float4 xr4 = *(const float4*)(xr + (v << 6) + c4);
  const float4 a4  = *(const float4*)(att + c4);
  const int beg = indptr[v];
  const int end = indptr[v + 1];
  float l = 0.f;
  float4 acc = {0.f, 0.f, 0.f, 0.f};
  int e = beg;
  for (; e + 4 <= end; e += 4) {
    const int s0 = csr[e + 0];
    const int s1 = csr[e + 1];
    const int s2 = csr[e + 2];
    const int s3 = csr[e + 3];
    const half4 h0 = *(const half4*)(xlp + (s0 << 6));
    const half4 h1 = *(const half4*)(xlp + (s1 << 6));
    const half4 h2 = *(const half4*)(xlp + (s2 << 6));
    const half4 h3 = *(const half4*)(xlp + (s3 << 6));
    const float4 x0 = {(float)h0.x, (float)h0.y, (float)h0.z, (float)h0.w};
    const float4 x1 = {(float)h1.x, (float)h1.y, (float)h1.z, (float)h1.w};
    const float4 x2 = {(float)h2.x, (float)h2.y, (float)h2.z, (float)h2.w};
    const float4 x3 = {(float)h3.x, (float)h3.y, (float)h3.z, (float)h3.w};
    float t0 = lrelu(x0.x + xr4.x) * a4.x + lrelu(x0.y + xr4.y) * a4.y
             + lrelu(x0.z + xr4.z) * a4.z + lrelu(x0.w + xr4.w) * a4.w;
    float t1 = lrelu(x1.x + xr4.x) * a4.x + lrelu(x1.y + xr4.y) * a4.y
             + lrelu(x1.z + xr4.z) * a4.z + lrelu(x1.w + xr4.w) * a4.w;
    float t2 = lrelu(x2.x + xr4.x) * a4.x + lrelu(x2.y + xr4.y) * a4.y
             + lrelu(x2.z + xr4.z) * a4.z + lrelu(x2.w + xr4.w) * a4.w;
    float t3 = lrelu(x3.x + xr4.x) * a4.x + lrelu(x3.y + xr4.y) * a4.y
             + lrelu(x3.z + xr4.z) * a4.z + lrelu(x3.w + xr4.w) * a4.w;
    t0 += __shfl_xor(t0, 1);  t1 += __shfl_xor(t1, 1);
    t2 += __shfl_xor(t2, 1);  t3 += __shfl_xor(t3, 1);
    t0 += __shfl_xor(t0, 2);  t1 += __shfl_xor(t1, 2);
    t2 += __shfl_xor(t2, 2);  t3 += __shfl_xor(t3, 2);
    t0 += __shfl_xor(t0, 4);  t1 += __shfl_xor(t1, 4);
    t2 += __shfl_xor(t2, 4);  t3 += __shfl_xor(t3, 4);
    t0 += __shfl_xor(t0, 8);  t1 += __shfl_xor(t1, 8);
    t2 += __shfl_xor(t2, 8);  t3 += __shfl_xor(t3, 8);
    const float p0 = __expf(t0);
    const float p1 = __expf(t1);
    const float p2 = __expf(t2);
    const float p3 = __expf(t3);
    l += (p0 + p1) + (p2 + p3);
    acc.x = fmaf(p0, x0.x, acc.x); acc.y = fmaf(p0, x0.y, acc.y);
    acc.z = fmaf(p0, x0.z, acc.z); acc.w = fmaf(p0, x0.w, acc.w);
    acc.x = fmaf(p1, x1.x, acc.x); acc.y = fmaf(p1, x1.y, acc.y);
    acc.z = fmaf(p1, x1.z, acc.z); acc.w = fmaf(p1, x1.w, acc.w);
    acc.x = fmaf(p2, x2.x, acc.x); acc.y = fmaf(p2, x2.y, acc.y);
    acc.z = fmaf(p2, x2.z, acc.z); acc.w = fmaf(p2, x2.w, acc.w);
    acc.x = fmaf(p3, x3.x, acc.x); acc.y = fmaf(p3, x3.y, acc.y);
    acc.z = fmaf(p3, x3.z, acc.z); acc.w = fmaf(p3, x3.w, acc.w);
  }
  for (; e < end; ++e) {
    const int s = csr[e];
    const half4 hv = *(const half4*)(xlp + (s << 6));
    const float4 xv = {(float)hv.x, (float)hv.y, (float)hv.z, (float)hv.w};
    float tt = lrelu(xv.x + xr4.x) * a4.x + lrelu(xv.y + xr4.y) * a4.y
             + lrelu(xv.z + xr4.z) * a4.z + lrelu(xv.w + xr4.w) * a4.w;
    tt += __shfl_xor(tt, 1);
    tt += __shfl_xor(tt, 2);
    tt += __shfl_xor(tt, 4);
    tt += __shfl_xor(tt, 8);
    const float p = __expf(tt);
    l += p;
    acc.x = fmaf(p, xv.x, acc.x); acc.y = fmaf(p, xv.y, acc.y);
    acc.z = fmaf(p, xv.z, acc.z); acc.w = fmaf(p, xv.w, acc.w);
  }
  const float rl = 1.f / l;
  const float4 b4 = *(const float4*)(bias + c4);
  float4 res;
  res.x = fmaf(acc.x, rl, b4.x);
  res.y = fmaf(acc.y, rl, b4.y);
  res.z = fmaf(acc.z, rl, b4.z);
  res.w = fmaf(acc.w, rl, b4.w);
  *(float4*)(out + (v << 6) + c4) = res;
}

extern "C" void kernel_launch(void* const* d_in, const int* in_sizes, int n_in,
                              void* d_out, int out_size, void* d_ws, size_t ws_size,
                              hipStream_t stream) {
  const float* x     = (const float*)d_in[0];
  const int*   ei    = (const int*)d_in[1];
  const float* Wl1   = (const float*)d_in[2];
  const float* bl1   = (const float*)d_in[3];
  const float* Wr1   = (const float*)d_in[4];
  const float* br1   = (const float*)d_in[5];
  const float* att1  = (const float*)d_in[6];
  const float* bias1 = (const float*)d_in[7];
  const float* Wl2   = (const float*)d_in[8];
  const float* bl2   = (const float*)d_in[9];
  const float* Wr2   = (const float*)d_in[10];
  const float* br2   = (const float*)d_in[11];
  const float* att2  = (const float*)d_in[12];
  const float* bias2 = (const float*)d_in[13];

  const int N  = in_sizes[0] / FIN;   // 100000
  const int E  = in_sizes[1] / 2;     // 1600000
  const int ET = E + N;
  const int NBKT = (N + BKT_SIZE - 1) >> BKT_SHIFT;   // 391 (<=512 required)

  // workspace layout
  _Float16* xl1h = (_Float16*)d_ws;                  // N*128 halfs (25.6 MB)
  float* xr1  = (float*)(xl1h + (size_t)N * F1);     // N*128 fp32
  float* hbuf = xr1 + (size_t)N * F1;                // N*128 fp32
  int* indptr = (int*)(hbuf + (size_t)N * F1);       // N+1
  int* csr    = indptr + (N + 1);                    // ET
  int* bcnt   = csr + ET;                            // 512
  int* bbase  = bcnt + 512;                          // 513
  int* bcur   = bbase + 513;                         // 512
  int* tmp    = (int*)hbuf;                          // alias: dead before attn1 writes hbuf
  _Float16* xl2h = xl1h;                             // reuse (xl1h dead after attn1)
  float* xr2  = xr1;                                 // reuse (xr1 dead after attn1)
  float* out  = (float*)d_out;

  const int sblocks = (ET + SCAT_CHUNK - 1) / SCAT_CHUNK;

  hipMemsetAsync(bcnt, 0, 512 * sizeof(int), stream);
  bucket_hist_kernel<<<sblocks, 256, 0, stream>>>(ei, bcnt, E, ET, NBKT);
  bucket_scan_kernel<<<1, 512, 0, stream>>>(bcnt, bbase, bcur, indptr, NBKT, N, ET);
  bucket_scatter_kernel<<<sblocks, 256, 0, stream>>>(ei, bcur, tmp, E, ET, NBKT);
  build_csr_kernel<<<NBKT, 256, 0, stream>>>(tmp, bbase, indptr, csr, N);

  dim3 g1((N + 63) / 64, F1 / 64, 2);
  gemm_bias2_kernel<<<g1, 256, 0, stream>>>(x, Wl1, bl1, xl1h, Wr1, br1, xr1, N, F1);

  attn1_kernel<<<(N + 7) / 8, 256, 0, stream>>>(xl1h, xr1, att1, bias1, indptr, csr, hbuf, N);

  dim3 g2((N + 63) / 64, C2 / 64, 2);
  gemm_bias2_kernel<<<g2, 256, 0, stream>>>(hbuf, Wl2, bl2, xl2h, Wr2, br2, xr2, N, C2);

  attn2_kernel<<<(N + 15) / 16, 256, 0, stream>>>(xl2h, xr2, att2, bias2, indptr, csr, out, N);
}

// Round 7
// 377.687 us; speedup vs baseline: 2.8071x; 1.1593x over previous
//
#include <hip/hip_runtime.h>
#include <math.h>

#define FIN 128   // input features (layer1 K, layer2 K)
#define F1  128   // H1*C1 = layer1 output width
#define C2  64    // layer2 output width
#define NEG 0.2f  // leaky_relu negative slope

#define BKT_SHIFT 8
#define BKT_SIZE  256     // nodes per bucket
#define SCAT_CHUNK 8192   // edges per block in hist/scatter
#define IMGCAP 8192       // LDS csr-image capacity (ints)

typedef _Float16 half4 __attribute__((ext_vector_type(4)));
typedef _Float16 f16x8 __attribute__((ext_vector_type(8)));
typedef float    f32x4 __attribute__((ext_vector_type(4)));

__device__ __forceinline__ float lrelu(float z) { return fmaxf(z, NEG * z); }

// ================= bucketed CSR build (dst-grouped, self-loops appended) =================
__global__ __launch_bounds__(256) void bucket_hist_kernel(
    const int* __restrict__ ei, int* __restrict__ bcnt, int E, int ET, int NBKT) {
  __shared__ int sh[512];
  const int t = threadIdx.x;
  for (int b = t; b < NBKT; b += 256) sh[b] = 0;
  __syncthreads();
  const int g0 = blockIdx.x * SCAT_CHUNK + t;
#pragma unroll
  for (int i = 0; i < 32; ++i) {
    const int g = g0 + i * 256;
    if (g < ET) {
      const int dst = (g < E) ? ei[E + g] : (g - E);
      atomicAdd(&sh[dst >> BKT_SHIFT], 1);
    }
  }
  __syncthreads();
  for (int b = t; b < NBKT; b += 256)
    if (sh[b]) atomicAdd(&bcnt[b], sh[b]);
}

__global__ __launch_bounds__(512) void bucket_scan_kernel(
    const int* __restrict__ bcnt, int* __restrict__ bbase, int* __restrict__ bcur,
    int* __restrict__ indptr, int NBKT, int N, int ET) {
  __shared__ int sh[512];
  const int t = threadIdx.x;
  const int v = (t < NBKT) ? bcnt[t] : 0;
  sh[t] = v;
  __syncthreads();
  for (int off = 1; off < 512; off <<= 1) {
    int val = (t >= off) ? sh[t - off] : 0;
    __syncthreads();
    sh[t] += val;
    __syncthreads();
  }
  const int excl = sh[t] - v;
  if (t < NBKT) { bbase[t] = excl; bcur[t] = excl; }
  if (t == NBKT - 1) bbase[NBKT] = excl + v;   // == ET
  if (t == 0) indptr[N] = ET;
}

__global__ __launch_bounds__(256) void bucket_scatter_kernel(
    const int* __restrict__ ei, int* __restrict__ bcur, int* __restrict__ tmp,
    int E, int ET, int NBKT) {
  __shared__ int sh_hist[512];
  __shared__ int sh_base[512];
  const int t = threadIdx.x;
  for (int b = t; b < NBKT; b += 256) sh_hist[b] = 0;
  __syncthreads();
  const int g0 = blockIdx.x * SCAT_CHUNK + t;
  int bk[32], pk[32];
#pragma unroll
  for (int i = 0; i < 32; ++i) {
    const int g = g0 + i * 256;
    int b = -1, p = 0;
    if (g < ET) {
      const int src = (g < E) ? ei[g] : (g - E);
      const int dst = (g < E) ? ei[E + g] : (g - E);
      b = dst >> BKT_SHIFT;
      p = (src << BKT_SHIFT) | (dst & (BKT_SIZE - 1));
      atomicAdd(&sh_hist[b], 1);
    }
    bk[i] = b; pk[i] = p;
  }
  __syncthreads();
  for (int b = t; b < NBKT; b += 256) {
    const int c = sh_hist[b];
    sh_base[b] = c ? atomicAdd(&bcur[b], c) : 0;
    sh_hist[b] = 0;   // reuse as in-block cursor
  }
  __syncthreads();
#pragma unroll
  for (int i = 0; i < 32; ++i) {
    if (bk[i] >= 0) {
      const int off = atomicAdd(&sh_hist[bk[i]], 1);
      tmp[sh_base[bk[i]] + off] = pk[i];
    }
  }
}

__global__ __launch_bounds__(256) void build_csr_kernel(
    const int* __restrict__ tmp, const int* __restrict__ bbase,
    int* __restrict__ indptr, int* __restrict__ csr, int N) {
  __shared__ int cnt[256];
  __shared__ int cur[256];
  __shared__ int img[IMGCAP];
  const int b = blockIdx.x;
  const int t = threadIdx.x;
  const int base = bbase[b];
  const int cntb = bbase[b + 1] - base;
  cnt[t] = 0;
  __syncthreads();
  for (int i = t; i < cntb; i += 256)
    atomicAdd(&cnt[tmp[base + i] & (BKT_SIZE - 1)], 1);
  __syncthreads();
  const int v = cnt[t];
  cur[t] = v;
  __syncthreads();
  for (int off = 1; off < 256; off <<= 1) {
    int val = (t >= off) ? cur[t - off] : 0;
    __syncthreads();
    cur[t] += val;
    __syncthreads();
  }
  const int excl = cur[t] - v;
  const int node = (b << BKT_SHIFT) + t;
  if (node < N) indptr[node] = base + excl;
  __syncthreads();
  cur[t] = excl;
  __syncthreads();
  if (cntb <= IMGCAP) {
    for (int i = t; i < cntb; i += 256) {
      const int p = tmp[base + i];
      const int pos = atomicAdd(&cur[p & (BKT_SIZE - 1)], 1);
      img[pos] = p >> BKT_SHIFT;
    }
    __syncthreads();
    for (int i = t; i < cntb; i += 256) csr[base + i] = img[i];
  } else {
    for (int i = t; i < cntb; i += 256) {
      const int p = tmp[base + i];
      const int pos = atomicAdd(&cur[p & (BKT_SIZE - 1)], 1);
      csr[base + pos] = p >> BKT_SHIFT;
    }
  }
}

// ---------------- fp32 -> fp16 convert (x) ----------------
__global__ __launch_bounds__(256) void conv_fp16_kernel(
    const float* __restrict__ src, _Float16* __restrict__ dst, int n4) {
  const int i = blockIdx.x * 256 + threadIdx.x;
  if (i < n4) {
    const float4 v = ((const float4*)src)[i];
    half4 h;
    h.x = (_Float16)v.x; h.y = (_Float16)v.y;
    h.z = (_Float16)v.z; h.w = (_Float16)v.w;
    ((half4*)dst)[i] = h;
  }
}

// ---------------- weight transpose+convert: Wt[n][128] = (fp16) W[k][n] ----------------
// blockIdx.y picks matrix: 0,1 -> 128x128; 2,3 -> 128x64
__global__ __launch_bounds__(256) void wtrans_kernel(
    const float* __restrict__ W0, const float* __restrict__ W1,
    const float* __restrict__ W2, const float* __restrict__ W3,
    _Float16* __restrict__ T0, _Float16* __restrict__ T1,
    _Float16* __restrict__ T2, _Float16* __restrict__ T3) {
  const int m = blockIdx.y;
  const float* W = (m == 0) ? W0 : (m == 1) ? W1 : (m == 2) ? W2 : W3;
  _Float16* T = (m == 0) ? T0 : (m == 1) ? T1 : (m == 2) ? T2 : T3;
  const int ncols = (m < 2) ? 128 : 64;
  const int idx = blockIdx.x * 256 + threadIdx.x;   // over ncols*128 (n,k)
  if (idx < ncols * 128) {
    const int n = idx >> 7;
    const int k = idx & 127;
    T[idx] = (_Float16)W[k * ncols + n];
  }
}

// ---------------- fp16 MFMA GEMM: O = A[M,128] @ W[128,NCOLS] + b ----------------
// LDS-free. Block = 4 waves; all waves share a 16-row tile, wave covers CPW col-tiles.
// z=0: fp16 output (xl path); z=1: fp32 output (xr path).
// Fragment layouts (v_mfma_f32_16x16x32_f16): A[row=lane&15][k=quad*8+j],
// B[k=quad*8+j][col=lane&15], D[row=quad*4+r][col=lane&15].
template<int NCOLS, int CPW>
__global__ __launch_bounds__(256) void gemm_mfma_kernel(
    const _Float16* __restrict__ A,
    const _Float16* __restrict__ Wt0, const float* __restrict__ b0, _Float16* __restrict__ O0,
    const _Float16* __restrict__ Wt1, const float* __restrict__ b1, float* __restrict__ O1,
    int M) {
  const int zsel = blockIdx.z;
  const _Float16* Wt = zsel ? Wt1 : Wt0;
  const float* bias  = zsel ? b1 : b0;
  const int wave = threadIdx.x >> 6;
  const int lane = threadIdx.x & 63;
  const int row16 = lane & 15;
  const int quad  = lane >> 4;
  const int kb = quad * 8;
  // hoist B fragments + bias (weights stay hot in L1)
  f16x8 bfrag[CPW][4];
  float bv[CPW];
#pragma unroll
  for (int c = 0; c < CPW; ++c) {
    const int n0 = (wave * CPW + c) * 16;
    bv[c] = bias[n0 + row16];
#pragma unroll
    for (int kt = 0; kt < 4; ++kt)
      bfrag[c][kt] = *(const f16x8*)(Wt + (n0 + row16) * 128 + kt * 32 + kb);
  }
  const int rowTiles = (M + 15) >> 4;
  for (int rt = blockIdx.x; rt < rowTiles; rt += gridDim.x) {
    const int r0 = rt << 4;
    const int arow = min(r0 + row16, M - 1);
    f16x8 afrag[4];
#pragma unroll
    for (int kt = 0; kt < 4; ++kt)
      afrag[kt] = *(const f16x8*)(A + (size_t)arow * 128 + kt * 32 + kb);
    f32x4 acc[CPW];
#pragma unroll
    for (int c = 0; c < CPW; ++c) acc[c] = (f32x4){0.f, 0.f, 0.f, 0.f};
#pragma unroll
    for (int kt = 0; kt < 4; ++kt)
#pragma unroll
      for (int c = 0; c < CPW; ++c)
        acc[c] = __builtin_amdgcn_mfma_f32_16x16x32_f16(afrag[kt], bfrag[c][kt], acc[c], 0, 0, 0);
#pragma unroll
    for (int c = 0; c < CPW; ++c) {
      const int col = (wave * CPW + c) * 16 + row16;
#pragma unroll
      for (int r = 0; r < 4; ++r) {
        const int row = r0 + quad * 4 + r;
        if (row < M) {
          const float val = acc[c][r] + bv[c];
          if (zsel) O1[(size_t)row * NCOLS + col] = val;
          else      O0[(size_t)row * NCOLS + col] = (_Float16)val;
        }
      }
    }
  }
}

// ---------------- layer 1 fused attention: fp16 gather, fp16 h output ----------------
// 256 threads = 8 nodes x 32 lanes; lane owns chans [4*lane .. 4*lane+3].
__global__ __launch_bounds__(256) void attn1_kernel(
    const _Float16* __restrict__ xl, const float* __restrict__ xr,
    const float* __restrict__ att, const float* __restrict__ bias,
    const int* __restrict__ indptr, const int* __restrict__ csr,
    _Float16* __restrict__ hout, int N) {
  const int lane = threadIdx.x & 31;
  const int v = blockIdx.x * 8 + (threadIdx.x >> 5);
  if (v >= N) return;
  const int c4 = lane << 2;
  const _Float16* xlp = xl + c4;
  const float4 xr4 = *(const float4*)(xr + (v << 7) + c4);
  const float4 a4  = *(const float4*)(att + c4);
  const int beg = indptr[v];
  const int end = indptr[v + 1];
  float l = 0.f;
  float4 acc = {0.f, 0.f, 0.f, 0.f};
  int e = beg;
  for (; e + 4 <= end; e += 4) {
    const int s0 = csr[e + 0];
    const int s1 = csr[e + 1];
    const int s2 = csr[e + 2];
    const int s3 = csr[e + 3];
    const half4 h0 = *(const half4*)(xlp + (s0 << 7));
    const half4 h1 = *(const half4*)(xlp + (s1 << 7));
    const half4 h2 = *(const half4*)(xlp + (s2 << 7));
    const half4 h3 = *(const half4*)(xlp + (s3 << 7));
    const float4 x0 = {(float)h0.x, (float)h0.y, (float)h0.z, (float)h0.w};
    const float4 x1 = {(float)h1.x, (float)h1.y, (float)h1.z, (float)h1.w};
    const float4 x2 = {(float)h2.x, (float)h2.y, (float)h2.z, (float)h2.w};
    const float4 x3 = {(float)h3.x, (float)h3.y, (float)h3.z, (float)h3.w};
    float t0 = lrelu(x0.x + xr4.x) * a4.x + lrelu(x0.y + xr4.y) * a4.y
             + lrelu(x0.z + xr4.z) * a4.z + lrelu(x0.w + xr4.w) * a4.w;
    float t1 = lrelu(x1.x + xr4.x) * a4.x + lrelu(x1.y + xr4.y) * a4.y
             + lrelu(x1.z + xr4.z) * a4.z + lrelu(x1.w + xr4.w) * a4.w;
    float t2 = lrelu(x2.x + xr4.x) * a4.x + lrelu(x2.y + xr4.y) * a4.y
             + lrelu(x2.z + xr4.z) * a4.z + lrelu(x2.w + xr4.w) * a4.w;
    float t3 = lrelu(x3.x + xr4.x) * a4.x + lrelu(x3.y + xr4.y) * a4.y
             + lrelu(x3.z + xr4.z) * a4.z + lrelu(x3.w + xr4.w) * a4.w;
    t0 += __shfl_xor(t0, 1);  t1 += __shfl_xor(t1, 1);
    t2 += __shfl_xor(t2, 1);  t3 += __shfl_xor(t3, 1);
    t0 += __shfl_xor(t0, 2);  t1 += __shfl_xor(t1, 2);
    t2 += __shfl_xor(t2, 2);  t3 += __shfl_xor(t3, 2);
    const float p0 = __expf(t0);
    const float p1 = __expf(t1);
    const float p2 = __expf(t2);
    const float p3 = __expf(t3);
    l += (p0 + p1) + (p2 + p3);
    acc.x = fmaf(p0, x0.x, acc.x); acc.y = fmaf(p0, x0.y, acc.y);
    acc.z = fmaf(p0, x0.z, acc.z); acc.w = fmaf(p0, x0.w, acc.w);
    acc.x = fmaf(p1, x1.x, acc.x); acc.y = fmaf(p1, x1.y, acc.y);
    acc.z = fmaf(p1, x1.z, acc.z); acc.w = fmaf(p1, x1.w, acc.w);
    acc.x = fmaf(p2, x2.x, acc.x); acc.y = fmaf(p2, x2.y, acc.y);
    acc.z = fmaf(p2, x2.z, acc.z); acc.w = fmaf(p2, x2.w, acc.w);
    acc.x = fmaf(p3, x3.x, acc.x); acc.y = fmaf(p3, x3.y, acc.y);
    acc.z = fmaf(p3, x3.z, acc.z); acc.w = fmaf(p3, x3.w, acc.w);
  }
  for (; e < end; ++e) {
    const int s = csr[e];
    const half4 hv = *(const half4*)(xlp + (s << 7));
    const float4 xv = {(float)hv.x, (float)hv.y, (float)hv.z, (float)hv.w};
    float tt = lrelu(xv.x + xr4.x) * a4.x + lrelu(xv.y + xr4.y) * a4.y
             + lrelu(xv.z + xr4.z) * a4.z + lrelu(xv.w + xr4.w) * a4.w;
    tt += __shfl_xor(tt, 1);
    tt += __shfl_xor(tt, 2);
    const float p = __expf(tt);
    l += p;
    acc.x = fmaf(p, xv.x, acc.x); acc.y = fmaf(p, xv.y, acc.y);
    acc.z = fmaf(p, xv.z, acc.z); acc.w = fmaf(p, xv.w, acc.w);
  }
  const float rl = 1.f / l;
  const float4 b4 = *(const float4*)(bias + c4);
  float4 res;
  res.x = fmaf(acc.x, rl, b4.x);
  res.y = fmaf(acc.y, rl, b4.y);
  res.z = fmaf(acc.z, rl, b4.z);
  res.w = fmaf(acc.w, rl, b4.w);
  res.x = res.x > 0.f ? res.x : expm1f(res.x);   // ELU
  res.y = res.y > 0.f ? res.y : expm1f(res.y);
  res.z = res.z > 0.f ? res.z : expm1f(res.z);
  res.w = res.w > 0.f ? res.w : expm1f(res.w);
  half4 hres;
  hres.x = (_Float16)res.x; hres.y = (_Float16)res.y;
  hres.z = (_Float16)res.z; hres.w = (_Float16)res.w;
  *(half4*)(hout + (v << 7) + c4) = hres;
}

// ---------------- layer 2 fused attention: fp16 gather, fp32 out ----------------
// 256 threads = 16 nodes x 16 lanes.
__global__ __launch_bounds__(256) void attn2_kernel(
    const _Float16* __restrict__ xl, const float* __restrict__ xr,
    const float* __restrict__ att, const float* __restrict__ bias,
    const int* __restrict__ indptr, const int* __restrict__ csr,
    float* __restrict__ out, int N) {
  const int lane = threadIdx.x & 15;
  const int v = blockIdx.x * 16 + (threadIdx.x >> 4);
  if (v >= N) return;
  const int c4 = lane << 2;
  const _Float16* xlp = xl + c4;
  const float4 xr4 = *(const float4*)(xr + (v << 6) + c4);
  const float4 a4  = *(const float4*)(att + c4);
  const int beg = indptr[v];
  const int end = indptr[v + 1];
  float l = 0.f;
  float4 acc = {0.f, 0.f, 0.f, 0.f};
  int e = beg;
  for (; e + 4 <= end; e += 4) {
    const int s0 = csr[e + 0];
    const int s1 = csr[e + 1];
    const int s2 = csr[e + 2];
    const int s3 = csr[e + 3];
    const half4 h0 = *(const half4*)(xlp + (s0 << 6));
    const half4 h1 = *(const half4*)(xlp + (s1 << 6));
    const half4 h2 = *(const half4*)(xlp + (s2 << 6));
    const half4 h3 = *(const half4*)(xlp + (s3 << 6));
    const float4 x0 = {(float)h0.x, (float)h0.y, (float)h0.z, (float)h0.w};
    const float4 x1 = {(float)h1.x, (float)h1.y, (float)h1.z, (float)h1.w};
    const float4 x2 = {(float)h2.x, (float)h2.y, (float)h2.z, (float)h2.w};
    const float4 x3 = {(float)h3.x, (float)h3.y, (float)h3.z, (float)h3.w};
    float t0 = lrelu(x0.x + xr4.x) * a4.x + lrelu(x0.y + xr4.y) * a4.y
             + lrelu(x0.z + xr4.z) * a4.z + lrelu(x0.w + xr4.w) * a4.w;
    float t1 = lrelu(x1.x + xr4.x) * a4.x + lrelu(x1.y + xr4.y) * a4.y
             + lrelu(x1.z + xr4.z) * a4.z + lrelu(x1.w + xr4.w) * a4.w;
    float t2 = lrelu(x2.x + xr4.x) * a4.x + lrelu(x2.y + xr4.y) * a4.y
             + lrelu(x2.z + xr4.z) * a4.z + lrelu(x2.w + xr4.w) * a4.w;
    float t3 = lrelu(x3.x + xr4.x) * a4.x + lrelu(x3.y + xr4.y) * a4.y
             + lrelu(x3.z + xr4.z) * a4.z + lrelu(x3.w + xr4.w) * a4.w;
    t0 += __shfl_xor(t0, 1);  t1 += __shfl_xor(t1, 1);
    t2 += __shfl_xor(t2, 1);  t3 += __shfl_xor(t3, 1);
    t0 += __shfl_xor(t0, 2);  t1 += __shfl_xor(t1, 2);
    t2 += __shfl_xor(t2, 2);  t3 += __shfl_xor(t3, 2);
    t0 += __shfl_xor(t0, 4);  t1 += __shfl_xor(t1, 4);
    t2 += __shfl_xor(t2, 4);  t3 += __shfl_xor(t3, 4);
    t0 += __shfl_xor(t0, 8);  t1 += __shfl_xor(t1, 8);
    t2 += __shfl_xor(t2, 8);  t3 += __shfl_xor(t3, 8);
    const float p0 = __expf(t0);
    const float p1 = __expf(t1);
    const float p2 = __expf(t2);
    const float p3 = __expf(t3);
    l += (p0 + p1) + (p2 + p3);
    acc.x = fmaf(p0, x0.x, acc.x); acc.y = fmaf(p0, x0.y, acc.y);
    acc.z = fmaf(p0, x0.z, acc.z); acc.w = fmaf(p0, x0.w, acc.w);
    acc.x = fmaf(p1, x1.x, acc.x); acc.y = fmaf(p1, x1.y, acc.y);
    acc.z = fmaf(p1, x1.z, acc.z); acc.w = fmaf(p1, x1.w, acc.w);
    acc.x = fmaf(p2, x2.x, acc.x); acc.y = fmaf(p2, x2.y, acc.y);
    acc.z = fmaf(p2, x2.z, acc.z); acc.w = fmaf(p2, x2.w, acc.w);
    acc.x = fmaf(p3, x3.x, acc.x); acc.y = fmaf(p3, x3.y, acc.y);
    acc.z = fmaf(p3, x3.z, acc.z); acc.w = fmaf(p3, x3.w, acc.w);
  }
  for (; e < end; ++e) {
    const int s = csr[e];
    const half4 hv = *(const half4*)(xlp + (s << 6));
    const float4 xv = {(float)hv.x, (float)hv.y, (float)hv.z, (float)hv.w};
    float tt = lrelu(xv.x + xr4.x) * a4.x + lrelu(xv.y + xr4.y) * a4.y
             + lrelu(xv.z + xr4.z) * a4.z + lrelu(xv.w + xr4.w) * a4.w;
    tt += __shfl_xor(tt, 1);
    tt += __shfl_xor(tt, 2);
    tt += __shfl_xor(tt, 4);
    tt += __shfl_xor(tt, 8);
    const float p = __expf(tt);
    l += p;
    acc.x = fmaf(p, xv.x, acc.x); acc.y = fmaf(p, xv.y, acc.y);
    acc.z = fmaf(p, xv.z, acc.z); acc.w = fmaf(p, xv.w, acc.w);
  }
  const float rl = 1.f / l;
  const float4 b4 = *(const float4*)(bias + c4);
  float4 res;
  res.x = fmaf(acc.x, rl, b4.x);
  res.y = fmaf(acc.y, rl, b4.y);
  res.z = fmaf(acc.z, rl, b4.z);
  res.w = fmaf(acc.w, rl, b4.w);
  *(float4*)(out + (v << 6) + c4) = res;
}

extern "C" void kernel_launch(void* const* d_in, const int* in_sizes, int n_in,
                              void* d_out, int out_size, void* d_ws, size_t ws_size,
                              hipStream_t stream) {
  const float* x     = (const float*)d_in[0];
  const int*   ei    = (const int*)d_in[1];
  const float* Wl1   = (const float*)d_in[2];
  const float* bl1   = (const float*)d_in[3];
  const float* Wr1   = (const float*)d_in[4];
  const float* br1   = (const float*)d_in[5];
  const float* att1  = (const float*)d_in[6];
  const float* bias1 = (const float*)d_in[7];
  const float* Wl2   = (const float*)d_in[8];
  const float* bl2   = (const float*)d_in[9];
  const float* Wr2   = (const float*)d_in[10];
  const float* br2   = (const float*)d_in[11];
  const float* att2  = (const float*)d_in[12];
  const float* bias2 = (const float*)d_in[13];

  const int N  = in_sizes[0] / FIN;   // 100000
  const int E  = in_sizes[1] / 2;     // 1600000
  const int ET = E + N;
  const int NBKT = (N + BKT_SIZE - 1) >> BKT_SHIFT;   // 391 (<=512 required)

  // workspace layout (16B-aligned blocks first)
  _Float16* xh    = (_Float16*)d_ws;                 // N*128 f16 (converted x)
  _Float16* xl1h  = xh + (size_t)N * FIN;            // N*128 f16
  float*    xr1   = (float*)(xl1h + (size_t)N * F1); // N*128 f32
  _Float16* hbufh = (_Float16*)(xr1 + (size_t)N * F1); // N*128 f16 (attn1 out)
  _Float16* Wt1l  = hbufh + (size_t)N * F1;          // 128*128 f16
  _Float16* Wt1r  = Wt1l + 128 * 128;                // 128*128 f16
  _Float16* Wt2l  = Wt1r + 128 * 128;                // 64*128 f16
  _Float16* Wt2r  = Wt2l + 64 * 128;                 // 64*128 f16
  int* indptr = (int*)(Wt2r + 64 * 128);             // N+1
  int* csr    = indptr + (N + 1);                    // ET
  int* bcnt   = csr + ET;                            // 512
  int* bbase  = bcnt + 512;                          // 513
  int* bcur   = bbase + 513;                         // 512
  int* tmp    = (int*)hbufh;   // alias: dead before attn1 writes hbufh (ET ints < N*128*2B)
  _Float16* xl2h = xl1h;                             // reuse (dead after attn1)
  float* xr2  = xr1;                                 // reuse (dead after attn1)
  float* out  = (float*)d_out;

  const int sblocks = (ET + SCAT_CHUNK - 1) / SCAT_CHUNK;

  hipMemsetAsync(bcnt, 0, 512 * sizeof(int), stream);
  bucket_hist_kernel<<<sblocks, 256, 0, stream>>>(ei, bcnt, E, ET, NBKT);
  bucket_scan_kernel<<<1, 512, 0, stream>>>(bcnt, bbase, bcur, indptr, NBKT, N, ET);
  bucket_scatter_kernel<<<sblocks, 256, 0, stream>>>(ei, bcur, tmp, E, ET, NBKT);
  build_csr_kernel<<<NBKT, 256, 0, stream>>>(tmp, bbase, indptr, csr, N);

  const int n4 = N * FIN / 4;
  conv_fp16_kernel<<<(n4 + 255) / 256, 256, 0, stream>>>(x, xh, n4);
  wtrans_kernel<<<dim3(64, 4), 256, 0, stream>>>(Wl1, Wr1, Wl2, Wr2, Wt1l, Wt1r, Wt2l, Wt2r);

  gemm_mfma_kernel<128, 2><<<dim3(1024, 1, 2), 256, 0, stream>>>(
      xh, Wt1l, bl1, xl1h, Wt1r, br1, xr1, N);

  attn1_kernel<<<(N + 7) / 8, 256, 0, stream>>>(xl1h, xr1, att1, bias1, indptr, csr, hbufh, N);

  gemm_mfma_kernel<64, 1><<<dim3(1024, 1, 2), 256, 0, stream>>>(
      hbufh, Wt2l, bl2, xl2h, Wt2r, br2, xr2, N);

  attn2_kernel<<<(N + 15) / 16, 256, 0, stream>>>(xl2h, xr2, att2, bias2, indptr, csr, out, N);
}

// Round 8
// 358.948 us; speedup vs baseline: 2.9537x; 1.0522x over previous
//
#include <hip/hip_runtime.h>
#include <math.h>

#define FIN 128   // input features (layer1 K, layer2 K)
#define F1  128   // H1*C1 = layer1 output width
#define C2  64    // layer2 output width
#define NEG 0.2f  // leaky_relu negative slope

#define BKT_SHIFT 8
#define BKT_SIZE  256     // nodes per bucket
#define SCAT_CHUNK 8192   // edges per block in hist/scatter
#define IMGCAP 8192       // LDS csr-image capacity (ints)

typedef _Float16 half4 __attribute__((ext_vector_type(4)));
typedef _Float16 f16x8 __attribute__((ext_vector_type(8)));
typedef _Float16 h2    __attribute__((ext_vector_type(2)));
typedef float    f32x4 __attribute__((ext_vector_type(4)));

union H8u { f16x8 v; h2 p[4]; };

__device__ __forceinline__ float lrelu(float z) { return fmaxf(z, NEG * z); }

// ================= bucketed CSR build (dst-grouped, self-loops appended) =================
__global__ __launch_bounds__(256) void bucket_hist_kernel(
    const int* __restrict__ ei, int* __restrict__ bcnt, int E, int ET, int NBKT) {
  __shared__ int sh[512];
  const int t = threadIdx.x;
  for (int b = t; b < NBKT; b += 256) sh[b] = 0;
  __syncthreads();
  const int g0 = blockIdx.x * SCAT_CHUNK + t;
#pragma unroll
  for (int i = 0; i < 32; ++i) {
    const int g = g0 + i * 256;
    if (g < ET) {
      const int dst = (g < E) ? ei[E + g] : (g - E);
      atomicAdd(&sh[dst >> BKT_SHIFT], 1);
    }
  }
  __syncthreads();
  for (int b = t; b < NBKT; b += 256)
    if (sh[b]) atomicAdd(&bcnt[b], sh[b]);
}

__global__ __launch_bounds__(512) void bucket_scan_kernel(
    const int* __restrict__ bcnt, int* __restrict__ bbase, int* __restrict__ bcur,
    int* __restrict__ indptr, int NBKT, int N, int ET) {
  __shared__ int sh[512];
  const int t = threadIdx.x;
  const int v = (t < NBKT) ? bcnt[t] : 0;
  sh[t] = v;
  __syncthreads();
  for (int off = 1; off < 512; off <<= 1) {
    int val = (t >= off) ? sh[t - off] : 0;
    __syncthreads();
    sh[t] += val;
    __syncthreads();
  }
  const int excl = sh[t] - v;
  if (t < NBKT) { bbase[t] = excl; bcur[t] = excl; }
  if (t == NBKT - 1) bbase[NBKT] = excl + v;   // == ET
  if (t == 0) indptr[N] = ET;
}

__global__ __launch_bounds__(256) void bucket_scatter_kernel(
    const int* __restrict__ ei, int* __restrict__ bcur, int* __restrict__ tmp,
    int E, int ET, int NBKT) {
  __shared__ int sh_hist[512];
  __shared__ int sh_base[512];
  const int t = threadIdx.x;
  for (int b = t; b < NBKT; b += 256) sh_hist[b] = 0;
  __syncthreads();
  const int g0 = blockIdx.x * SCAT_CHUNK + t;
  int bk[32], pk[32];
#pragma unroll
  for (int i = 0; i < 32; ++i) {
    const int g = g0 + i * 256;
    int b = -1, p = 0;
    if (g < ET) {
      const int src = (g < E) ? ei[g] : (g - E);
      const int dst = (g < E) ? ei[E + g] : (g - E);
      b = dst >> BKT_SHIFT;
      p = (src << BKT_SHIFT) | (dst & (BKT_SIZE - 1));
      atomicAdd(&sh_hist[b], 1);
    }
    bk[i] = b; pk[i] = p;
  }
  __syncthreads();
  for (int b = t; b < NBKT; b += 256) {
    const int c = sh_hist[b];
    sh_base[b] = c ? atomicAdd(&bcur[b], c) : 0;
    sh_hist[b] = 0;   // reuse as in-block cursor
  }
  __syncthreads();
#pragma unroll
  for (int i = 0; i < 32; ++i) {
    if (bk[i] >= 0) {
      const int off = atomicAdd(&sh_hist[bk[i]], 1);
      tmp[sh_base[bk[i]] + off] = pk[i];
    }
  }
}

__global__ __launch_bounds__(256) void build_csr_kernel(
    const int* __restrict__ tmp, const int* __restrict__ bbase,
    int* __restrict__ indptr, int* __restrict__ csr, int N) {
  __shared__ int cnt[256];
  __shared__ int cur[256];
  __shared__ int img[IMGCAP];
  const int b = blockIdx.x;
  const int t = threadIdx.x;
  const int base = bbase[b];
  const int cntb = bbase[b + 1] - base;
  cnt[t] = 0;
  __syncthreads();
  for (int i = t; i < cntb; i += 256)
    atomicAdd(&cnt[tmp[base + i] & (BKT_SIZE - 1)], 1);
  __syncthreads();
  const int v = cnt[t];
  cur[t] = v;
  __syncthreads();
  for (int off = 1; off < 256; off <<= 1) {
    int val = (t >= off) ? cur[t - off] : 0;
    __syncthreads();
    cur[t] += val;
    __syncthreads();
  }
  const int excl = cur[t] - v;
  const int node = (b << BKT_SHIFT) + t;
  if (node < N) indptr[node] = base + excl;
  __syncthreads();
  cur[t] = excl;
  __syncthreads();
  if (cntb <= IMGCAP) {
    for (int i = t; i < cntb; i += 256) {
      const int p = tmp[base + i];
      const int pos = atomicAdd(&cur[p & (BKT_SIZE - 1)], 1);
      img[pos] = p >> BKT_SHIFT;
    }
    __syncthreads();
    for (int i = t; i < cntb; i += 256) csr[base + i] = img[i];
  } else {
    for (int i = t; i < cntb; i += 256) {
      const int p = tmp[base + i];
      const int pos = atomicAdd(&cur[p & (BKT_SIZE - 1)], 1);
      csr[base + pos] = p >> BKT_SHIFT;
    }
  }
}

// ---------------- fp32 -> fp16 convert (x) ----------------
__global__ __launch_bounds__(256) void conv_fp16_kernel(
    const float* __restrict__ src, _Float16* __restrict__ dst, int n4) {
  const int i = blockIdx.x * 256 + threadIdx.x;
  if (i < n4) {
    const float4 v = ((const float4*)src)[i];
    half4 h;
    h.x = (_Float16)v.x; h.y = (_Float16)v.y;
    h.z = (_Float16)v.z; h.w = (_Float16)v.w;
    ((half4*)dst)[i] = h;
  }
}

// ---------------- weight transpose+convert: Wt[n][128] = (fp16) W[k][n] ----------------
__global__ __launch_bounds__(256) void wtrans_kernel(
    const float* __restrict__ W0, const float* __restrict__ W1,
    const float* __restrict__ W2, const float* __restrict__ W3,
    _Float16* __restrict__ T0, _Float16* __restrict__ T1,
    _Float16* __restrict__ T2, _Float16* __restrict__ T3) {
  const int m = blockIdx.y;
  const float* W = (m == 0) ? W0 : (m == 1) ? W1 : (m == 2) ? W2 : W3;
  _Float16* T = (m == 0) ? T0 : (m == 1) ? T1 : (m == 2) ? T2 : T3;
  const int ncols = (m < 2) ? 128 : 64;
  const int idx = blockIdx.x * 256 + threadIdx.x;   // over ncols*128 (n,k)
  if (idx < ncols * 128) {
    const int n = idx >> 7;
    const int k = idx & 127;
    T[idx] = (_Float16)W[k * ncols + n];
  }
}

// ---------------- fp16 MFMA GEMM: O = A[M,128] @ W[128,NCOLS] + b, fp16 out ----------------
// LDS-free. Block = 4 waves; all waves share a 16-row tile, wave covers CPW col-tiles.
template<int NCOLS, int CPW>
__global__ __launch_bounds__(256) void gemm_mfma_kernel(
    const _Float16* __restrict__ A,
    const _Float16* __restrict__ Wt0, const float* __restrict__ b0, _Float16* __restrict__ O0,
    const _Float16* __restrict__ Wt1, const float* __restrict__ b1, _Float16* __restrict__ O1,
    int M) {
  const int zsel = blockIdx.z;
  const _Float16* Wt = zsel ? Wt1 : Wt0;
  const float* bias  = zsel ? b1 : b0;
  _Float16* O        = zsel ? O1 : O0;
  const int wave = threadIdx.x >> 6;
  const int lane = threadIdx.x & 63;
  const int row16 = lane & 15;
  const int quad  = lane >> 4;
  const int kb = quad * 8;
  f16x8 bfrag[CPW][4];
  float bv[CPW];
#pragma unroll
  for (int c = 0; c < CPW; ++c) {
    const int n0 = (wave * CPW + c) * 16;
    bv[c] = bias[n0 + row16];
#pragma unroll
    for (int kt = 0; kt < 4; ++kt)
      bfrag[c][kt] = *(const f16x8*)(Wt + (n0 + row16) * 128 + kt * 32 + kb);
  }
  const int rowTiles = (M + 15) >> 4;
  for (int rt = blockIdx.x; rt < rowTiles; rt += gridDim.x) {
    const int r0 = rt << 4;
    const int arow = min(r0 + row16, M - 1);
    f16x8 afrag[4];
#pragma unroll
    for (int kt = 0; kt < 4; ++kt)
      afrag[kt] = *(const f16x8*)(A + (size_t)arow * 128 + kt * 32 + kb);
    f32x4 acc[CPW];
#pragma unroll
    for (int c = 0; c < CPW; ++c) acc[c] = (f32x4){0.f, 0.f, 0.f, 0.f};
#pragma unroll
    for (int kt = 0; kt < 4; ++kt)
#pragma unroll
      for (int c = 0; c < CPW; ++c)
        acc[c] = __builtin_amdgcn_mfma_f32_16x16x32_f16(afrag[kt], bfrag[c][kt], acc[c], 0, 0, 0);
#pragma unroll
    for (int c = 0; c < CPW; ++c) {
      const int col = (wave * CPW + c) * 16 + row16;
#pragma unroll
      for (int r = 0; r < 4; ++r) {
        const int row = r0 + quad * 4 + r;
        if (row < M)
          O[(size_t)row * NCOLS + col] = (_Float16)(acc[c][r] + bv[c]);
      }
    }
  }
}

// ---------------- layer 1 fused attention: 16 lanes/node x 8 chans, packed fp16 ----------------
// Head = 16 chans = lane pair; score reduce = 1 shfl stage.
__global__ __launch_bounds__(256) void attn1_kernel(
    const _Float16* __restrict__ xl, const _Float16* __restrict__ xr,
    const float* __restrict__ att, const float* __restrict__ bias,
    const int* __restrict__ indptr, const int* __restrict__ csr,
    _Float16* __restrict__ hout, int N) {
  const int lane = threadIdx.x & 15;
  const int v = blockIdx.x * 16 + (threadIdx.x >> 4);
  if (v >= N) return;
  const int c8 = lane << 3;
  const _Float16* xlp = xl + c8;
  H8u xru; xru.v = *(const f16x8*)(xr + (v << 7) + c8);
  H8u atu;
  {
    const float4 a0 = *(const float4*)(att + c8);
    const float4 a1 = *(const float4*)(att + c8 + 4);
    f16x8 a;
    a[0] = (_Float16)a0.x; a[1] = (_Float16)a0.y; a[2] = (_Float16)a0.z; a[3] = (_Float16)a0.w;
    a[4] = (_Float16)a1.x; a[5] = (_Float16)a1.y; a[6] = (_Float16)a1.z; a[7] = (_Float16)a1.w;
    atu.v = a;
  }
  const h2 neg2 = {(_Float16)NEG, (_Float16)NEG};
  const h2 zero2 = {(_Float16)0.f, (_Float16)0.f};
  const int beg = indptr[v];
  const int end = indptr[v + 1];
  float l = 0.f;
  float acc[8] = {0.f, 0.f, 0.f, 0.f, 0.f, 0.f, 0.f, 0.f};
  int e = beg;
  for (; e + 4 <= end; e += 4) {
    const int s0 = csr[e + 0];
    const int s1 = csr[e + 1];
    const int s2 = csr[e + 2];
    const int s3 = csr[e + 3];
    H8u x0, x1, x2, x3;
    x0.v = *(const f16x8*)(xlp + (s0 << 7));
    x1.v = *(const f16x8*)(xlp + (s1 << 7));
    x2.v = *(const f16x8*)(xlp + (s2 << 7));
    x3.v = *(const f16x8*)(xlp + (s3 << 7));
    h2 sa0 = zero2, sa1 = zero2, sa2 = zero2, sa3 = zero2;
#pragma unroll
    for (int j = 0; j < 4; ++j) {
      h2 e0 = x0.p[j] + xru.p[j];
      h2 e1 = x1.p[j] + xru.p[j];
      h2 e2 = x2.p[j] + xru.p[j];
      h2 e3 = x3.p[j] + xru.p[j];
      e0 = __builtin_elementwise_max(e0, e0 * neg2);
      e1 = __builtin_elementwise_max(e1, e1 * neg2);
      e2 = __builtin_elementwise_max(e2, e2 * neg2);
      e3 = __builtin_elementwise_max(e3, e3 * neg2);
      sa0 = e0 * atu.p[j] + sa0;
      sa1 = e1 * atu.p[j] + sa1;
      sa2 = e2 * atu.p[j] + sa2;
      sa3 = e3 * atu.p[j] + sa3;
    }
    float t0 = (float)sa0[0] + (float)sa0[1];
    float t1 = (float)sa1[0] + (float)sa1[1];
    float t2 = (float)sa2[0] + (float)sa2[1];
    float t3 = (float)sa3[0] + (float)sa3[1];
    t0 += __shfl_xor(t0, 1);  t1 += __shfl_xor(t1, 1);
    t2 += __shfl_xor(t2, 1);  t3 += __shfl_xor(t3, 1);
    const float p0 = __expf(t0);
    const float p1 = __expf(t1);
    const float p2 = __expf(t2);
    const float p3 = __expf(t3);
    l += (p0 + p1) + (p2 + p3);
#pragma unroll
    for (int j = 0; j < 4; ++j) {
      acc[2*j]   = fmaf(p0, (float)x0.p[j][0], acc[2*j]);
      acc[2*j+1] = fmaf(p0, (float)x0.p[j][1], acc[2*j+1]);
      acc[2*j]   = fmaf(p1, (float)x1.p[j][0], acc[2*j]);
      acc[2*j+1] = fmaf(p1, (float)x1.p[j][1], acc[2*j+1]);
      acc[2*j]   = fmaf(p2, (float)x2.p[j][0], acc[2*j]);
      acc[2*j+1] = fmaf(p2, (float)x2.p[j][1], acc[2*j+1]);
      acc[2*j]   = fmaf(p3, (float)x3.p[j][0], acc[2*j]);
      acc[2*j+1] = fmaf(p3, (float)x3.p[j][1], acc[2*j+1]);
    }
  }
  for (; e < end; ++e) {
    const int s = csr[e];
    H8u xv; xv.v = *(const f16x8*)(xlp + (s << 7));
    h2 sa = zero2;
#pragma unroll
    for (int j = 0; j < 4; ++j) {
      h2 ev = xv.p[j] + xru.p[j];
      ev = __builtin_elementwise_max(ev, ev * neg2);
      sa = ev * atu.p[j] + sa;
    }
    float tt = (float)sa[0] + (float)sa[1];
    tt += __shfl_xor(tt, 1);
    const float p = __expf(tt);
    l += p;
#pragma unroll
    for (int j = 0; j < 4; ++j) {
      acc[2*j]   = fmaf(p, (float)xv.p[j][0], acc[2*j]);
      acc[2*j+1] = fmaf(p, (float)xv.p[j][1], acc[2*j+1]);
    }
  }
  const float rl = 1.f / l;
  const float4 b0 = *(const float4*)(bias + c8);
  const float4 b1 = *(const float4*)(bias + c8 + 4);
  float r[8];
  r[0] = fmaf(acc[0], rl, b0.x); r[1] = fmaf(acc[1], rl, b0.y);
  r[2] = fmaf(acc[2], rl, b0.z); r[3] = fmaf(acc[3], rl, b0.w);
  r[4] = fmaf(acc[4], rl, b1.x); r[5] = fmaf(acc[5], rl, b1.y);
  r[6] = fmaf(acc[6], rl, b1.z); r[7] = fmaf(acc[7], rl, b1.w);
  f16x8 hres;
#pragma unroll
  for (int i = 0; i < 8; ++i) {
    const float z = r[i] > 0.f ? r[i] : expm1f(r[i]);   // ELU
    hres[i] = (_Float16)z;
  }
  *(f16x8*)(hout + (v << 7) + c8) = hres;
}

// ---------------- layer 2 fused attention: 8 lanes/node x 8 chans, packed fp16 ----------------
// 1 head over 64 chans -> 3 shfl stages over the 8-lane group.
__global__ __launch_bounds__(256) void attn2_kernel(
    const _Float16* __restrict__ xl, const _Float16* __restrict__ xr,
    const float* __restrict__ att, const float* __restrict__ bias,
    const int* __restrict__ indptr, const int* __restrict__ csr,
    float* __restrict__ out, int N) {
  const int lane = threadIdx.x & 7;
  const int v = blockIdx.x * 32 + (threadIdx.x >> 3);
  if (v >= N) return;
  const int c8 = lane << 3;
  const _Float16* xlp = xl + c8;
  H8u xru; xru.v = *(const f16x8*)(xr + (v << 6) + c8);
  H8u atu;
  {
    const float4 a0 = *(const float4*)(att + c8);
    const float4 a1 = *(const float4*)(att + c8 + 4);
    f16x8 a;
    a[0] = (_Float16)a0.x; a[1] = (_Float16)a0.y; a[2] = (_Float16)a0.z; a[3] = (_Float16)a0.w;
    a[4] = (_Float16)a1.x; a[5] = (_Float16)a1.y; a[6] = (_Float16)a1.z; a[7] = (_Float16)a1.w;
    atu.v = a;
  }
  const h2 neg2 = {(_Float16)NEG, (_Float16)NEG};
  const h2 zero2 = {(_Float16)0.f, (_Float16)0.f};
  const int beg = indptr[v];
  const int end = indptr[v + 1];
  float l = 0.f;
  float acc[8] = {0.f, 0.f, 0.f, 0.f, 0.f, 0.f, 0.f, 0.f};
  int e = beg;
  for (; e + 4 <= end; e += 4) {
    const int s0 = csr[e + 0];
    const int s1 = csr[e + 1];
    const int s2 = csr[e + 2];
    const int s3 = csr[e + 3];
    H8u x0, x1, x2, x3;
    x0.v = *(const f16x8*)(xlp + (s0 << 6));
    x1.v = *(const f16x8*)(xlp + (s1 << 6));
    x2.v = *(const f16x8*)(xlp + (s2 << 6));
    x3.v = *(const f16x8*)(xlp + (s3 << 6));
    h2 sa0 = zero2, sa1 = zero2, sa2 = zero2, sa3 = zero2;
#pragma unroll
    for (int j = 0; j < 4; ++j) {
      h2 e0 = x0.p[j] + xru.p[j];
      h2 e1 = x1.p[j] + xru.p[j];
      h2 e2 = x2.p[j] + xru.p[j];
      h2 e3 = x3.p[j] + xru.p[j];
      e0 = __builtin_elementwise_max(e0, e0 * neg2);
      e1 = __builtin_elementwise_max(e1, e1 * neg2);
      e2 = __builtin_elementwise_max(e2, e2 * neg2);
      e3 = __builtin_elementwise_max(e3, e3 * neg2);
      sa0 = e0 * atu.p[j] + sa0;
      sa1 = e1 * atu.p[j] + sa1;
      sa2 = e2 * atu.p[j] + sa2;
      sa3 = e3 * atu.p[j] + sa3;
    }
    float t0 = (float)sa0[0] + (float)sa0[1];
    float t1 = (float)sa1[0] + (float)sa1[1];
    float t2 = (float)sa2[0] + (float)sa2[1];
    float t3 = (float)sa3[0] + (float)sa3[1];
    t0 += __shfl_xor(t0, 1);  t1 += __shfl_xor(t1, 1);
    t2 += __shfl_xor(t2, 1);  t3 += __shfl_xor(t3, 1);
    t0 += __shfl_xor(t0, 2);  t1 += __shfl_xor(t1, 2);
    t2 += __shfl_xor(t2, 2);  t3 += __shfl_xor(t3, 2);
    t0 += __shfl_xor(t0, 4);  t1 += __shfl_xor(t1, 4);
    t2 += __shfl_xor(t2, 4);  t3 += __shfl_xor(t3, 4);
    const float p0 = __expf(t0);
    const float p1 = __expf(t1);
    const float p2 = __expf(t2);
    const float p3 = __expf(t3);
    l += (p0 + p1) + (p2 + p3);
#pragma unroll
    for (int j = 0; j < 4; ++j) {
      acc[2*j]   = fmaf(p0, (float)x0.p[j][0], acc[2*j]);
      acc[2*j+1] = fmaf(p0, (float)x0.p[j][1], acc[2*j+1]);
      acc[2*j]   = fmaf(p1, (float)x1.p[j][0], acc[2*j]);
      acc[2*j+1] = fmaf(p1, (float)x1.p[j][1], acc[2*j+1]);
      acc[2*j]   = fmaf(p2, (float)x2.p[j][0], acc[2*j]);
      acc[2*j+1] = fmaf(p2, (float)x2.p[j][1], acc[2*j+1]);
      acc[2*j]   = fmaf(p3, (float)x3.p[j][0], acc[2*j]);
      acc[2*j+1] = fmaf(p3, (float)x3.p[j][1], acc[2*j+1]);
    }
  }
  for (; e < end; ++e) {
    const int s = csr[e];
    H8u xv; xv.v = *(const f16x8*)(xlp + (s << 6));
    h2 sa = zero2;
#pragma unroll
    for (int j = 0; j < 4; ++j) {
      h2 ev = xv.p[j] + xru.p[j];
      ev = __builtin_elementwise_max(ev, ev * neg2);
      sa = ev * atu.p[j] + sa;
    }
    float tt = (float)sa[0] + (float)sa[1];
    tt += __shfl_xor(tt, 1);
    tt += __shfl_xor(tt, 2);
    tt += __shfl_xor(tt, 4);
    const float p = __expf(tt);
    l += p;
#pragma unroll
    for (int j = 0; j < 4; ++j) {
      acc[2*j]   = fmaf(p, (float)xv.p[j][0], acc[2*j]);
      acc[2*j+1] = fmaf(p, (float)xv.p[j][1], acc[2*j+1]);
    }
  }
  const float rl = 1.f / l;
  const float4 b0 = *(const float4*)(bias + c8);
  const float4 b1 = *(const float4*)(bias + c8 + 4);
  float4 o0, o1;
  o0.x = fmaf(acc[0], rl, b0.x); o0.y = fmaf(acc[1], rl, b0.y);
  o0.z = fmaf(acc[2], rl, b0.z); o0.w = fmaf(acc[3], rl, b0.w);
  o1.x = fmaf(acc[4], rl, b1.x); o1.y = fmaf(acc[5], rl, b1.y);
  o1.z = fmaf(acc[6], rl, b1.z); o1.w = fmaf(acc[7], rl, b1.w);
  *(float4*)(out + (v << 6) + c8) = o0;
  *(float4*)(out + (v << 6) + c8 + 4) = o1;
}

extern "C" void kernel_launch(void* const* d_in, const int* in_sizes, int n_in,
                              void* d_out, int out_size, void* d_ws, size_t ws_size,
                              hipStream_t stream) {
  const float* x     = (const float*)d_in[0];
  const int*   ei    = (const int*)d_in[1];
  const float* Wl1   = (const float*)d_in[2];
  const float* bl1   = (const float*)d_in[3];
  const float* Wr1   = (const float*)d_in[4];
  const float* br1   = (const float*)d_in[5];
  const float* att1  = (const float*)d_in[6];
  const float* bias1 = (const float*)d_in[7];
  const float* Wl2   = (const float*)d_in[8];
  const float* bl2   = (const float*)d_in[9];
  const float* Wr2   = (const float*)d_in[10];
  const float* br2   = (const float*)d_in[11];
  const float* att2  = (const float*)d_in[12];
  const float* bias2 = (const float*)d_in[13];

  const int N  = in_sizes[0] / FIN;   // 100000
  const int E  = in_sizes[1] / 2;     // 1600000
  const int ET = E + N;
  const int NBKT = (N + BKT_SIZE - 1) >> BKT_SHIFT;   // 391 (<=512 required)

  // workspace layout
  _Float16* xh    = (_Float16*)d_ws;                   // N*128 f16
  _Float16* xl1h  = xh + (size_t)N * FIN;              // N*128 f16
  _Float16* xr1h  = xl1h + (size_t)N * F1;             // N*128 f16
  _Float16* hbufh = xr1h + (size_t)N * F1;             // N*128 f16
  _Float16* Wt1l  = hbufh + (size_t)N * F1;            // 128*128 f16
  _Float16* Wt1r  = Wt1l + 128 * 128;
  _Float16* Wt2l  = Wt1r + 128 * 128;                  // 64*128 f16
  _Float16* Wt2r  = Wt2l + 64 * 128;
  int* indptr = (int*)(Wt2r + 64 * 128);               // N+1
  int* csr    = indptr + (N + 1);                      // ET
  int* bcnt   = csr + ET;                              // 512
  int* bbase  = bcnt + 512;                            // 513
  int* bcur   = bbase + 513;                           // 512
  int* tmp    = (int*)hbufh;   // alias: dead before attn1 writes hbufh
  _Float16* xl2h = xl1h;                               // reuse after attn1
  _Float16* xr2h = xr1h;
  float* out  = (float*)d_out;

  const int sblocks = (ET + SCAT_CHUNK - 1) / SCAT_CHUNK;

  hipMemsetAsync(bcnt, 0, 512 * sizeof(int), stream);
  bucket_hist_kernel<<<sblocks, 256, 0, stream>>>(ei, bcnt, E, ET, NBKT);
  bucket_scan_kernel<<<1, 512, 0, stream>>>(bcnt, bbase, bcur, indptr, NBKT, N, ET);
  bucket_scatter_kernel<<<sblocks, 256, 0, stream>>>(ei, bcur, tmp, E, ET, NBKT);
  build_csr_kernel<<<NBKT, 256, 0, stream>>>(tmp, bbase, indptr, csr, N);

  const int n4 = N * FIN / 4;
  conv_fp16_kernel<<<(n4 + 255) / 256, 256, 0, stream>>>(x, xh, n4);
  wtrans_kernel<<<dim3(64, 4), 256, 0, stream>>>(Wl1, Wr1, Wl2, Wr2, Wt1l, Wt1r, Wt2l, Wt2r);

  gemm_mfma_kernel<128, 2><<<dim3(1024, 1, 2), 256, 0, stream>>>(
      xh, Wt1l, bl1, xl1h, Wt1r, br1, xr1h, N);

  attn1_kernel<<<(N + 15) / 16, 256, 0, stream>>>(xl1h, xr1h, att1, bias1, indptr, csr, hbufh, N);

  gemm_mfma_kernel<64, 1><<<dim3(1024, 1, 2), 256, 0, stream>>>(
      hbufh, Wt2l, bl2, xl2h, Wt2r, br2, xr2h, N);

  attn2_kernel<<<(N + 31) / 32, 256, 0, stream>>>(xl2h, xr2h, att2, bias2, indptr, csr, out, N);
}